// Round 1
// baseline (1603.442 us; speedup 1.0000x reference)
//
#include <hip/hip_runtime.h>
#include <math.h>

typedef unsigned short u16;
typedef unsigned int   u32;
typedef __attribute__((ext_vector_type(4))) float f32x4;
typedef __attribute__((ext_vector_type(8))) short bf16x8;

#define M_TOK 50176
#define CDIM  384

__device__ __forceinline__ u16 f2b(float f){
  union { float f; u32 u; } v; v.f = f;
  u32 r = v.u + 0x7fffu + ((v.u >> 16) & 1u);
  return (u16)(r >> 16);
}
__device__ __forceinline__ float b2f(u16 h){
  union { u32 u; float f; } v; v.u = ((u32)h) << 16; return v.f;
}
__device__ __forceinline__ u32 pack2(float a, float b){
  return (u32)f2b(a) | ((u32)f2b(b) << 16);
}
__device__ __forceinline__ void unpk(u32 u, float& a, float& b){
  union { u32 x; float f; } lo, hi;
  lo.x = u << 16; hi.x = u & 0xffff0000u;
  a = lo.f; b = hi.f;
}

__device__ __forceinline__ void gload_lds16(const u16* g, u16* l){
  __builtin_amdgcn_global_load_lds((const __attribute__((address_space(1))) u32*)g,
                                   (__attribute__((address_space(3))) u32*)l, 16, 0, 0);
}

// ---------------- weight convert f32 -> bf16 ----------------
__global__ void cvtw(const float* __restrict__ in, u16* __restrict__ out, int n4){
  int i = blockIdx.x * 256 + threadIdx.x;
  if (i < n4){
    float4 v = ((const float4*)in)[i];
    uint2 o; o.x = pack2(v.x, v.y); o.y = pack2(v.z, v.w);
    ((uint2*)out)[i] = o;
  }
}

// ---------------- LayerNorm (fp32 in, bf16 out) ----------------
__global__ __launch_bounds__(256) void ln_kernel(
    const float* __restrict__ x, const float* __restrict__ g,
    const float* __restrict__ b, u16* __restrict__ out, int ntok)
{
  int wave = threadIdx.x >> 6, lane = threadIdx.x & 63;
  for (long t = blockIdx.x * 4 + wave; t < ntok; t += (long)gridDim.x * 4){
    const float* xr = x + t * CDIM;
    float v[6]; float s = 0.f, ss = 0.f;
    #pragma unroll
    for (int j = 0; j < 6; ++j){ v[j] = xr[j*64 + lane]; s += v[j]; ss += v[j]*v[j]; }
    #pragma unroll
    for (int o = 32; o >= 1; o >>= 1){ s += __shfl_xor(s, o); ss += __shfl_xor(ss, o); }
    float mean = s * (1.f/384.f);
    float var  = ss * (1.f/384.f) - mean*mean;
    float rs   = rsqrtf(var + 1e-5f);
    #pragma unroll
    for (int j = 0; j < 6; ++j){
      int c = j*64 + lane;
      out[t*CDIM + c] = f2b((v[j] - mean) * rs * g[c] + b[c]);
    }
  }
}

// ---------------- GEMM out[m,n] = sum_k A[m,k]*W[n,k] (+bias, epilogue) ----
// EPI 0: bf16 store (bias)   1: bf16 store (bias+exact gelu)   2: f32 store (bias + resid)
template<int EPI>
__global__ __launch_bounds__(256, 2) void gemm_bt(
    const u16* __restrict__ A, const u16* __restrict__ Wt,
    const float* __restrict__ bias, const float* __restrict__ resid,
    void* __restrict__ outp, int M, int N, int K)
{
  __shared__ __align__(16) u16 lA[128*32];
  __shared__ __align__(16) u16 lB[128*32];
  const int tid  = threadIdx.x;
  const int wave = tid >> 6, lane = tid & 63;
  const int bm = blockIdx.x, bn = blockIdx.y;
  const int wr = wave >> 1, wc = wave & 1;
  const int l15 = lane & 15, l4 = lane >> 4;

  f32x4 acc[4][4] = {};

  for (int kt = 0; kt < K; kt += 32){
    #pragma unroll
    for (int it = 0; it < 2; ++it){
      int flat = it*256 + tid;
      int row = flat >> 2, ch = flat & 3;
      const u16* ga = A  + (long)(bm*128 + row) * K + kt + ch*8;
      const u16* gb = Wt + (long)(bn*128 + row) * K + kt + ch*8;
      gload_lds16(ga, &lA[(it*256 + wave*64) * 8]);
      gload_lds16(gb, &lB[(it*256 + wave*64) * 8]);
    }
    __syncthreads();
    bf16x8 af[4], bfr[4];
    #pragma unroll
    for (int mi = 0; mi < 4; ++mi)
      af[mi] = *(const bf16x8*)&lA[(wr*64 + mi*16 + l15)*32 + l4*8];
    #pragma unroll
    for (int ni = 0; ni < 4; ++ni)
      bfr[ni] = *(const bf16x8*)&lB[(wc*64 + ni*16 + l15)*32 + l4*8];
    #pragma unroll
    for (int mi = 0; mi < 4; ++mi)
      #pragma unroll
      for (int ni = 0; ni < 4; ++ni)
        acc[mi][ni] = __builtin_amdgcn_mfma_f32_16x16x32_bf16(af[mi], bfr[ni], acc[mi][ni], 0, 0, 0);
    __syncthreads();
  }

  #pragma unroll
  for (int ni = 0; ni < 4; ++ni){
    int col = bn*128 + wc*64 + ni*16 + l15;
    float bb = bias[col];
    #pragma unroll
    for (int mi = 0; mi < 4; ++mi){
      int row0 = bm*128 + wr*64 + mi*16 + l4*4;
      #pragma unroll
      for (int r = 0; r < 4; ++r){
        long off = (long)(row0 + r) * N + col;
        float v = acc[mi][ni][r] + bb;
        if (EPI == 0){
          ((u16*)outp)[off] = f2b(v);
        } else if (EPI == 1){
          ((u16*)outp)[off] = f2b(0.5f * v * (1.f + erff(v * 0.70710678118654752f)));
        } else {
          ((float*)outp)[off] = resid[off] + v;
        }
      }
    }
  }
}

// ---------------- windowed attention, one (window, head) per 64-thr block ----
template<int SHIFT>
__global__ __launch_bounds__(64) void attn_kernel(
    const u16* __restrict__ qkv,      // [ntok][1152] bf16
    const float* __restrict__ rpb_i,  // [169][12]
    const int* __restrict__ rel_idx,  // [49][49]
    const float* __restrict__ mask,   // [64][49][49]
    u16* __restrict__ attn_out)       // [ntok][384] bf16
{
  __shared__ float k_lds[49*36];
  __shared__ float v_lds[49*36];
  const int bid  = blockIdx.x;
  const int head = bid % 12;
  const int win  = bid / 12;
  const int b    = win >> 6;
  const int wl   = win & 63;
  const int wy   = wl >> 3, wx = wl & 7;
  const int n    = threadIdx.x;

  long t = 0;
  float q[32];
  if (n < 49){
    int r = n / 7, c = n % 7;
    int hh = (wy*7 + r + SHIFT) % 56;
    int ww = (wx*7 + c + SHIFT) % 56;
    t = (long)b * 3136 + hh * 56 + ww;
    const uint4* qp = (const uint4*)(qkv + t*1152 + head*32);
    const uint4* kp = (const uint4*)(qkv + t*1152 + 384 + head*32);
    const uint4* vp = (const uint4*)(qkv + t*1152 + 768 + head*32);
    #pragma unroll
    for (int c4 = 0; c4 < 4; ++c4){
      uint4 u = qp[c4];
      unpk(u.x, q[c4*8+0], q[c4*8+1]); unpk(u.y, q[c4*8+2], q[c4*8+3]);
      unpk(u.z, q[c4*8+4], q[c4*8+5]); unpk(u.w, q[c4*8+6], q[c4*8+7]);
    }
    #pragma unroll
    for (int c4 = 0; c4 < 4; ++c4){
      uint4 u = kp[c4];
      float a0,a1,a2,a3,a4,a5,a6,a7;
      unpk(u.x,a0,a1); unpk(u.y,a2,a3); unpk(u.z,a4,a5); unpk(u.w,a6,a7);
      *(float4*)&k_lds[n*36 + c4*8]     = make_float4(a0,a1,a2,a3);
      *(float4*)&k_lds[n*36 + c4*8 + 4] = make_float4(a4,a5,a6,a7);
    }
    #pragma unroll
    for (int c4 = 0; c4 < 4; ++c4){
      uint4 u = vp[c4];
      float a0,a1,a2,a3,a4,a5,a6,a7;
      unpk(u.x,a0,a1); unpk(u.y,a2,a3); unpk(u.z,a4,a5); unpk(u.w,a6,a7);
      *(float4*)&v_lds[n*36 + c4*8]     = make_float4(a0,a1,a2,a3);
      *(float4*)&v_lds[n*36 + c4*8 + 4] = make_float4(a4,a5,a6,a7);
    }
  }
  __syncthreads();
  if (n < 49){
    float s[49];
    const int* ridx = rel_idx + n*49;
    const float* mrow = mask + (long)wl*2401 + n*49;
    #pragma unroll
    for (int m = 0; m < 49; ++m){
      float dot = 0.f;
      const float4* kr = (const float4*)&k_lds[m*36];
      #pragma unroll
      for (int kk = 0; kk < 8; ++kk){
        float4 kv = kr[kk];
        dot += q[kk*4+0]*kv.x + q[kk*4+1]*kv.y + q[kk*4+2]*kv.z + q[kk*4+3]*kv.w;
      }
      float sm = dot * 0.17677669529663687f + rpb_i[ridx[m]*12 + head];
      if (SHIFT) sm += mrow[m];
      s[m] = sm;
    }
    float mx = s[0];
    #pragma unroll
    for (int m = 1; m < 49; ++m) mx = fmaxf(mx, s[m]);
    float den = 0.f;
    #pragma unroll
    for (int m = 0; m < 49; ++m){ s[m] = __expf(s[m] - mx); den += s[m]; }
    float inv = 1.f / den;
    float o[32];
    #pragma unroll
    for (int d = 0; d < 32; ++d) o[d] = 0.f;
    #pragma unroll
    for (int m = 0; m < 49; ++m){
      float pm = s[m];
      const float4* vr = (const float4*)&v_lds[m*36];
      #pragma unroll
      for (int d4 = 0; d4 < 8; ++d4){
        float4 vv = vr[d4];
        o[d4*4+0] += pm*vv.x; o[d4*4+1] += pm*vv.y;
        o[d4*4+2] += pm*vv.z; o[d4*4+3] += pm*vv.w;
      }
    }
    uint4* op = (uint4*)(attn_out + t*384 + head*32);
    #pragma unroll
    for (int c4 = 0; c4 < 4; ++c4){
      uint4 w;
      w.x = pack2(o[c4*8+0]*inv, o[c4*8+1]*inv);
      w.y = pack2(o[c4*8+2]*inv, o[c4*8+3]*inv);
      w.z = pack2(o[c4*8+4]*inv, o[c4*8+5]*inv);
      w.w = pack2(o[c4*8+6]*inv, o[c4*8+7]*inv);
      op[c4] = w;
    }
  }
}

extern "C" void kernel_launch(void* const* d_in, const int* in_sizes, int n_in,
                              void* d_out, int out_size, void* d_ws, size_t ws_size,
                              hipStream_t stream)
{
  const float* x_in   = (const float*)d_in[0];
  const float* mask   = (const float*)d_in[1];
  const int*   relidx = (const int*)d_in[2];
  const float* n1g    = (const float*)d_in[3];
  const float* n1b    = (const float*)d_in[4];
  const float* qkvw   = (const float*)d_in[5];
  const float* qkvb   = (const float*)d_in[6];
  const float* rpb    = (const float*)d_in[7];
  const float* pw     = (const float*)d_in[8];
  const float* pb     = (const float*)d_in[9];
  const float* n2g    = (const float*)d_in[10];
  const float* n2b    = (const float*)d_in[11];
  const float* f1w    = (const float*)d_in[12];
  const float* f1b    = (const float*)d_in[13];
  const float* f2w    = (const float*)d_in[14];
  const float* f2bb   = (const float*)d_in[15];
  float* xout = (float*)d_out;

  char* ws = (char*)d_ws;
  u16* wqkv  = (u16*)ws; ws += (size_t)2*1152*384*2;
  u16* wproj = (u16*)ws; ws += (size_t)2*384*384*2;
  u16* wfc1  = (u16*)ws; ws += (size_t)2*1536*384*2;
  u16* wfc2  = (u16*)ws; ws += (size_t)2*384*1536*2;
  u16* bufA  = (u16*)ws; ws += (size_t)M_TOK*1536*2;   // qkv (1152) / h (1536)
  u16* bufB  = (u16*)ws; ws += (size_t)M_TOK*384*2;    // xn / attn_out / h_in

  // convert weights to bf16
  {
    int n;
    n = 2*1152*384;  cvtw<<<dim3((n/4+255)/256), dim3(256), 0, stream>>>(qkvw, wqkv, n/4);
    n = 2*384*384;   cvtw<<<dim3((n/4+255)/256), dim3(256), 0, stream>>>(pw,   wproj, n/4);
    n = 2*1536*384;  cvtw<<<dim3((n/4+255)/256), dim3(256), 0, stream>>>(f1w,  wfc1, n/4);
    n = 2*384*1536;  cvtw<<<dim3((n/4+255)/256), dim3(256), 0, stream>>>(f2w,  wfc2, n/4);
  }

  for (int i = 0; i < 2; ++i){
    const float* xi = (i == 0) ? x_in : xout;
    // LN1 -> bufB (bf16)
    ln_kernel<<<dim3(2048), dim3(256), 0, stream>>>(xi, n1g + i*384, n1b + i*384, bufB, M_TOK);
    // QKV: bufB @ wqkv^T -> bufA  [M,1152]
    gemm_bt<0><<<dim3(392, 9), dim3(256), 0, stream>>>(
        bufB, wqkv + (size_t)i*1152*384, qkvb + i*1152, nullptr, bufA, M_TOK, 1152, 384);
    // attention: bufA -> bufB [M,384]
    if (i == 0)
      attn_kernel<0><<<dim3(12288), dim3(64), 0, stream>>>(bufA, rpb, relidx, mask, bufB);
    else
      attn_kernel<3><<<dim3(12288), dim3(64), 0, stream>>>(bufA, rpb + 169*12, relidx, mask, bufB);
    // proj + residual: xout = xi + bufB @ wproj^T + pb   [M,384] f32
    gemm_bt<2><<<dim3(392, 3), dim3(256), 0, stream>>>(
        bufB, wproj + (size_t)i*384*384, pb + i*384, xi, xout, M_TOK, 384, 384);
    // LN2 -> bufB (bf16)
    ln_kernel<<<dim3(2048), dim3(256), 0, stream>>>(xout, n2g + i*384, n2b + i*384, bufB, M_TOK);
    // FC1 + gelu: bufB @ wfc1^T -> bufA [M,1536] bf16
    gemm_bt<1><<<dim3(392, 12), dim3(256), 0, stream>>>(
        bufB, wfc1 + (size_t)i*1536*384, f1b + i*1536, nullptr, bufA, M_TOK, 1536, 384);
    // FC2 + residual: xout += bufA @ wfc2^T + f2b  [M,384] f32
    gemm_bt<2><<<dim3(392, 3), dim3(256), 0, stream>>>(
        bufA, wfc2 + (size_t)i*384*1536, f2bb + i*384, xout, xout, M_TOK, 384, 1536);
  }
  (void)in_sizes; (void)n_in; (void)out_size; (void)ws_size;
}

// Round 2
// 1190.391 us; speedup vs baseline: 1.3470x; 1.3470x over previous
//
#include <hip/hip_runtime.h>
#include <math.h>

typedef unsigned short u16;
typedef unsigned int   u32;
typedef __attribute__((ext_vector_type(4))) float f32x4;
typedef __attribute__((ext_vector_type(8))) short bf16x8;

#define M_TOK 50176
#define CDIM  384

__device__ __forceinline__ u16 f2b(float f){
  union { float f; u32 u; } v; v.f = f;
  u32 r = v.u + 0x7fffu + ((v.u >> 16) & 1u);
  return (u16)(r >> 16);
}
__device__ __forceinline__ u32 pack2(float a, float b){
  return (u32)f2b(a) | ((u32)f2b(b) << 16);
}

__device__ __forceinline__ void gload_lds16(const u16* g, u16* l){
  __builtin_amdgcn_global_load_lds((const __attribute__((address_space(1))) u32*)g,
                                   (__attribute__((address_space(3))) u32*)l, 16, 0, 0);
}

// ---------------- weight convert f32 -> bf16 ----------------
__global__ void cvtw(const float* __restrict__ in, u16* __restrict__ out, int n4){
  int i = blockIdx.x * 256 + threadIdx.x;
  if (i < n4){
    float4 v = ((const float4*)in)[i];
    uint2 o; o.x = pack2(v.x, v.y); o.y = pack2(v.z, v.w);
    ((uint2*)out)[i] = o;
  }
}

// ---------------- LayerNorm (fp32 in, bf16 out) ----------------
__global__ __launch_bounds__(256) void ln_kernel(
    const float* __restrict__ x, const float* __restrict__ g,
    const float* __restrict__ b, u16* __restrict__ out, int ntok)
{
  int wave = threadIdx.x >> 6, lane = threadIdx.x & 63;
  for (long t = blockIdx.x * 4 + wave; t < ntok; t += (long)gridDim.x * 4){
    const float* xr = x + t * CDIM;
    float v[6]; float s = 0.f, ss = 0.f;
    #pragma unroll
    for (int j = 0; j < 6; ++j){ v[j] = xr[j*64 + lane]; s += v[j]; ss += v[j]*v[j]; }
    #pragma unroll
    for (int o = 32; o >= 1; o >>= 1){ s += __shfl_xor(s, o); ss += __shfl_xor(ss, o); }
    float mean = s * (1.f/384.f);
    float var  = ss * (1.f/384.f) - mean*mean;
    float rs   = rsqrtf(var + 1e-5f);
    #pragma unroll
    for (int j = 0; j < 6; ++j){
      int c = j*64 + lane;
      out[t*CDIM + c] = f2b((v[j] - mean) * rs * g[c] + b[c]);
    }
  }
}

// ---------------- GEMM out[m,n] = sum_k A[m,k]*W[n,k] (+bias, epilogue) ----
// EPI 0: bf16 store (bias)   1: bf16 store (bias+exact gelu)   2: f32 store (bias + resid)
template<int EPI>
__global__ __launch_bounds__(256, 2) void gemm_bt(
    const u16* __restrict__ A, const u16* __restrict__ Wt,
    const float* __restrict__ bias, const float* __restrict__ resid,
    void* __restrict__ outp, int M, int N, int K)
{
  __shared__ __align__(16) u16 lA[128*32];
  __shared__ __align__(16) u16 lB[128*32];
  const int tid  = threadIdx.x;
  const int wave = tid >> 6, lane = tid & 63;
  const int bm = blockIdx.x, bn = blockIdx.y;
  const int wr = wave >> 1, wc = wave & 1;
  const int l15 = lane & 15, l4 = lane >> 4;

  f32x4 acc[4][4] = {};

  for (int kt = 0; kt < K; kt += 32){
    #pragma unroll
    for (int it = 0; it < 2; ++it){
      int flat = it*256 + tid;
      int row = flat >> 2, ch = flat & 3;
      const u16* ga = A  + (long)(bm*128 + row) * K + kt + ch*8;
      const u16* gb = Wt + (long)(bn*128 + row) * K + kt + ch*8;
      gload_lds16(ga, &lA[(it*256 + wave*64) * 8]);
      gload_lds16(gb, &lB[(it*256 + wave*64) * 8]);
    }
    __syncthreads();
    bf16x8 af[4], bfr[4];
    #pragma unroll
    for (int mi = 0; mi < 4; ++mi)
      af[mi] = *(const bf16x8*)&lA[(wr*64 + mi*16 + l15)*32 + l4*8];
    #pragma unroll
    for (int ni = 0; ni < 4; ++ni)
      bfr[ni] = *(const bf16x8*)&lB[(wc*64 + ni*16 + l15)*32 + l4*8];
    #pragma unroll
    for (int mi = 0; mi < 4; ++mi)
      #pragma unroll
      for (int ni = 0; ni < 4; ++ni)
        acc[mi][ni] = __builtin_amdgcn_mfma_f32_16x16x32_bf16(af[mi], bfr[ni], acc[mi][ni], 0, 0, 0);
    __syncthreads();
  }

  #pragma unroll
  for (int ni = 0; ni < 4; ++ni){
    int col = bn*128 + wc*64 + ni*16 + l15;
    float bb = bias[col];
    #pragma unroll
    for (int mi = 0; mi < 4; ++mi){
      int row0 = bm*128 + wr*64 + mi*16 + l4*4;
      #pragma unroll
      for (int r = 0; r < 4; ++r){
        long off = (long)(row0 + r) * N + col;
        float v = acc[mi][ni][r] + bb;
        if (EPI == 0){
          ((u16*)outp)[off] = f2b(v);
        } else if (EPI == 1){
          ((u16*)outp)[off] = f2b(0.5f * v * (1.f + erff(v * 0.70710678118654752f)));
        } else {
          ((float*)outp)[off] = resid[off] + v;
        }
      }
    }
  }
}

// ---------------- bias table: btbl[h][q][l15*4+ni] = rpb[ridx[q][key]][h],
//                  key = ni*16+l15; -1e9 for q>=49 or key>=49 (padding mask)
__global__ void build_btbl(const float* __restrict__ rpb, const int* __restrict__ ridx,
                           float* __restrict__ btbl){
  int q = blockIdx.x & 63, h = blockIdx.x >> 6;
  int l = threadIdx.x;
  float v = -1e9f;
  if (q < 49){
    int key = (l & 3) * 16 + (l >> 2);
    if (key < 49) v = rpb[ridx[q*49 + key] * 12 + h];
  }
  btbl[(h*64 + q)*64 + l] = v;
}

// ---------------- MFMA windowed attention: one wave = one (window, head) ----
template<int SHIFT>
__global__ __launch_bounds__(64) void attn_mfma(
    const u16* __restrict__ qkv,     // [M_TOK][1152] bf16
    const float* __restrict__ btbl,  // [12][64][64] f32 (this block's table)
    u16* __restrict__ attn_out)      // [M_TOK][384] bf16
{
  __shared__ __align__(16) u16 p_lds[64*72];   // P[q][m] bf16, stride 72
  __shared__ __align__(16) u16 vt_lds[32*72];  // V^T[d][m] bf16, stride 72
  __shared__ int tok_lds[64];
  __shared__ int rid_lds[64];

  const int bid = blockIdx.x;
  const int h   = bid % 12;
  const int win = bid / 12;
  const int b   = win >> 6, wl = win & 63;
  const int wy  = wl >> 3,  wx = wl & 7;
  const int lane = threadIdx.x;
  const int l15 = lane & 15, l4 = lane >> 4;

  auto tokof = [&](int n)->int{
    int r = (n * 9363) >> 16;      // n/7 for n<=48
    int c = n - r * 7;
    int hh = wy*7 + r + SHIFT; if (hh >= 56) hh -= 56;
    int ww = wx*7 + c + SHIFT; if (ww >= 56) ww -= 56;
    return b*3136 + hh*56 + ww;
  };

  // ---- staging: V^T (zero-padded cols >=49), token table, region ids ----
  {
    const int n  = lane;
    const int nc = n < 49 ? n : 48;
    const int t  = tokof(nc);
    tok_lds[n] = t;
    if (SHIFT){
      int r = (nc * 9363) >> 16, c = nc - r*7;
      int gh = wy*7 + r, gw = wx*7 + c;
      int rh = gh <= 48 ? 0 : (gh <= 52 ? 1 : 2);
      int rw = gw <= 48 ? 0 : (gw <= 52 ? 1 : 2);
      rid_lds[n] = rh*3 + rw;
    }
    const uint4* vp = (const uint4*)(qkv + (size_t)t*1152 + 768 + h*32);
    u32 w[16];
    #pragma unroll
    for (int j4 = 0; j4 < 4; ++j4){
      uint4 u = vp[j4];
      w[j4*4+0]=u.x; w[j4*4+1]=u.y; w[j4*4+2]=u.z; w[j4*4+3]=u.w;
    }
    if (n >= 49){
      #pragma unroll
      for (int j = 0; j < 16; ++j) w[j] = 0;
    }
    #pragma unroll
    for (int j = 0; j < 16; ++j){
      vt_lds[(2*j  )*72 + n] = (u16)(w[j] & 0xffffu);
      vt_lds[(2*j+1)*72 + n] = (u16)(w[j] >> 16);
    }
  }

  // ---- QK^T fragments directly from global ----
  bf16x8 qa[4], kb[4];
  #pragma unroll
  for (int mi = 0; mi < 4; ++mi){
    int row = mi*16 + l15; int t = tokof(row < 49 ? row : 48);
    qa[mi] = *(const bf16x8*)(qkv + (size_t)t*1152 + h*32 + l4*8);
  }
  #pragma unroll
  for (int ni = 0; ni < 4; ++ni){
    int row = ni*16 + l15; int t = tokof(row < 49 ? row : 48);
    kb[ni] = *(const bf16x8*)(qkv + (size_t)t*1152 + 384 + h*32 + l4*8);
  }
  f32x4 s[4][4] = {};
  #pragma unroll
  for (int mi = 0; mi < 4; ++mi)
    #pragma unroll
    for (int ni = 0; ni < 4; ++ni)
      s[mi][ni] = __builtin_amdgcn_mfma_f32_16x16x32_bf16(qa[mi], kb[ni], s[mi][ni], 0, 0, 0);

  __syncthreads();   // staging (V^T / tok / rid) complete

  int rid_k[4];
  if (SHIFT){
    #pragma unroll
    for (int ni = 0; ni < 4; ++ni) rid_k[ni] = rid_lds[ni*16 + l15];
  }

  // ---- scale + bias + mask, row softmax in-register ----
  const float* bt = btbl + h*4096;
  float mx[4][4], den[4][4];
  #pragma unroll
  for (int mi = 0; mi < 4; ++mi){
    #pragma unroll
    for (int r = 0; r < 4; ++r){
      int q = mi*16 + l4*4 + r;
      f32x4 bq = *(const f32x4*)(bt + q*64 + l15*4);
      int ridq = 0;
      if (SHIFT) ridq = rid_lds[q];
      #pragma unroll
      for (int ni = 0; ni < 4; ++ni){
        float v = s[mi][ni][r] * 0.17677669529663687f + bq[ni];
        if (SHIFT) v += (ridq == rid_k[ni]) ? 0.f : -100.f;
        s[mi][ni][r] = v;
      }
      float m0 = fmaxf(fmaxf(s[mi][0][r], s[mi][1][r]), fmaxf(s[mi][2][r], s[mi][3][r]));
      #pragma unroll
      for (int o = 1; o <= 8; o <<= 1) m0 = fmaxf(m0, __shfl_xor(m0, o));
      float d0 = 0.f;
      #pragma unroll
      for (int ni = 0; ni < 4; ++ni){
        float e = __expf(s[mi][ni][r] - m0);
        s[mi][ni][r] = e; d0 += e;
      }
      #pragma unroll
      for (int o = 1; o <= 8; o <<= 1) d0 += __shfl_xor(d0, o);
      mx[mi][r] = m0; den[mi][r] = d0;
    }
  }

  // ---- pack P to LDS (bf16, stride 72) ----
  #pragma unroll
  for (int mi = 0; mi < 4; ++mi)
    #pragma unroll
    for (int r = 0; r < 4; ++r){
      int q = mi*16 + l4*4 + r;
      #pragma unroll
      for (int ni = 0; ni < 4; ++ni)
        p_lds[q*72 + ni*16 + l15] = f2b(s[mi][ni][r]);
    }

  __syncthreads();   // P writes complete

  // ---- PV via MFMA: O[q][d] = sum_m P[q][m] * VT[d][m] ----
  f32x4 o2[4][2] = {};
  #pragma unroll
  for (int ks = 0; ks < 2; ++ks){
    bf16x8 vb[2];
    #pragma unroll
    for (int ni = 0; ni < 2; ++ni)
      vb[ni] = *(const bf16x8*)&vt_lds[(ni*16 + l15)*72 + ks*32 + l4*8];
    #pragma unroll
    for (int mi = 0; mi < 4; ++mi){
      bf16x8 pa = *(const bf16x8*)&p_lds[(mi*16 + l15)*72 + ks*32 + l4*8];
      #pragma unroll
      for (int ni = 0; ni < 2; ++ni)
        o2[mi][ni] = __builtin_amdgcn_mfma_f32_16x16x32_bf16(pa, vb[ni], o2[mi][ni], 0, 0, 0);
    }
  }

  // ---- scaled store (only valid query rows) ----
  #pragma unroll
  for (int mi = 0; mi < 4; ++mi){
    #pragma unroll
    for (int r = 0; r < 4; ++r){
      int q = mi*16 + l4*4 + r;
      if (q < 49){
        float inv = 1.f / den[mi][r];
        long t = tok_lds[q];
        #pragma unroll
        for (int ni = 0; ni < 2; ++ni){
          int d = ni*16 + l15;
          attn_out[t*384 + h*32 + d] = f2b(o2[mi][ni][r] * inv);
        }
      }
    }
  }
  (void)mx;
}

extern "C" void kernel_launch(void* const* d_in, const int* in_sizes, int n_in,
                              void* d_out, int out_size, void* d_ws, size_t ws_size,
                              hipStream_t stream)
{
  const float* x_in   = (const float*)d_in[0];
  const int*   relidx = (const int*)d_in[2];
  const float* n1g    = (const float*)d_in[3];
  const float* n1b    = (const float*)d_in[4];
  const float* qkvw   = (const float*)d_in[5];
  const float* qkvb   = (const float*)d_in[6];
  const float* rpb    = (const float*)d_in[7];
  const float* pw     = (const float*)d_in[8];
  const float* pb     = (const float*)d_in[9];
  const float* n2g    = (const float*)d_in[10];
  const float* n2b    = (const float*)d_in[11];
  const float* f1w    = (const float*)d_in[12];
  const float* f1b    = (const float*)d_in[13];
  const float* f2w    = (const float*)d_in[14];
  const float* f2bb   = (const float*)d_in[15];
  float* xout = (float*)d_out;

  char* ws = (char*)d_ws;
  u16* wqkv  = (u16*)ws; ws += (size_t)2*1152*384*2;
  u16* wproj = (u16*)ws; ws += (size_t)2*384*384*2;
  u16* wfc1  = (u16*)ws; ws += (size_t)2*1536*384*2;
  u16* wfc2  = (u16*)ws; ws += (size_t)2*384*1536*2;
  u16* bufA  = (u16*)ws; ws += (size_t)M_TOK*1536*2;   // qkv (1152) / h (1536)
  u16* bufB  = (u16*)ws; ws += (size_t)M_TOK*384*2;    // xn / attn_out / h_in
  // bias table lives in the unused tail of bufA during attention:
  // bufA holds qkv [M][1152]; tail M*384*2 bytes >> 196KB needed.
  float* btbl = (float*)(bufA + (size_t)M_TOK*1152);

  // convert weights to bf16
  {
    int n;
    n = 2*1152*384;  cvtw<<<dim3((n/4+255)/256), dim3(256), 0, stream>>>(qkvw, wqkv, n/4);
    n = 2*384*384;   cvtw<<<dim3((n/4+255)/256), dim3(256), 0, stream>>>(pw,   wproj, n/4);
    n = 2*1536*384;  cvtw<<<dim3((n/4+255)/256), dim3(256), 0, stream>>>(f1w,  wfc1, n/4);
    n = 2*384*1536;  cvtw<<<dim3((n/4+255)/256), dim3(256), 0, stream>>>(f2w,  wfc2, n/4);
  }

  for (int i = 0; i < 2; ++i){
    const float* xi = (i == 0) ? x_in : xout;
    // LN1 -> bufB (bf16)
    ln_kernel<<<dim3(2048), dim3(256), 0, stream>>>(xi, n1g + i*384, n1b + i*384, bufB, M_TOK);
    // QKV: bufB @ wqkv^T -> bufA  [M,1152]
    gemm_bt<0><<<dim3(392, 9), dim3(256), 0, stream>>>(
        bufB, wqkv + (size_t)i*1152*384, qkvb + i*1152, nullptr, bufA, M_TOK, 1152, 384);
    // bias table for this block (tail of bufA is free: qkv uses only 1152 of 1536)
    build_btbl<<<dim3(768), dim3(64), 0, stream>>>(rpb + (size_t)i*169*12, relidx, btbl);
    // attention: bufA -> bufB [M,384]
    if (i == 0)
      attn_mfma<0><<<dim3(12288), dim3(64), 0, stream>>>(bufA, btbl, bufB);
    else
      attn_mfma<3><<<dim3(12288), dim3(64), 0, stream>>>(bufA, btbl, bufB);
    // proj + residual: xout = xi + bufB @ wproj^T + pb   [M,384] f32
    gemm_bt<2><<<dim3(392, 3), dim3(256), 0, stream>>>(
        bufB, wproj + (size_t)i*384*384, pb + i*384, xi, xout, M_TOK, 384, 384);
    // LN2 -> bufB (bf16)
    ln_kernel<<<dim3(2048), dim3(256), 0, stream>>>(xout, n2g + i*384, n2b + i*384, bufB, M_TOK);
    // FC1 + gelu: bufB @ wfc1^T -> bufA [M,1536] bf16
    gemm_bt<1><<<dim3(392, 12), dim3(256), 0, stream>>>(
        bufB, wfc1 + (size_t)i*1536*384, f1b + i*1536, nullptr, bufA, M_TOK, 1536, 384);
    // FC2 + residual: xout += bufA @ wfc2^T + f2b  [M,384] f32
    gemm_bt<2><<<dim3(392, 3), dim3(256), 0, stream>>>(
        bufA, wfc2 + (size_t)i*384*1536, f2bb + i*384, xout, xout, M_TOK, 384, 1536);
  }
  (void)in_sizes; (void)n_in; (void)out_size; (void)ws_size;
}

// Round 3
// 1059.646 us; speedup vs baseline: 1.5132x; 1.1234x over previous
//
#include <hip/hip_runtime.h>
#include <math.h>

typedef unsigned short u16;
typedef unsigned int   u32;
typedef __attribute__((ext_vector_type(4))) float f32x4;
typedef __attribute__((ext_vector_type(8))) short bf16x8;

#define M_TOK 50176
#define CDIM  384

__device__ __forceinline__ u16 f2b(float f){
  union { float f; u32 u; } v; v.f = f;
  u32 r = v.u + 0x7fffu + ((v.u >> 16) & 1u);
  return (u16)(r >> 16);
}
__device__ __forceinline__ u32 pack2(float a, float b){
  return (u32)f2b(a) | ((u32)f2b(b) << 16);
}

__device__ __forceinline__ void gload_lds16(const u16* g, u16* l){
  __builtin_amdgcn_global_load_lds((const __attribute__((address_space(1))) u32*)g,
                                   (__attribute__((address_space(3))) u32*)l, 16, 0, 0);
}

// ---------------- weight convert f32 -> bf16 ----------------
__global__ void cvtw(const float* __restrict__ in, u16* __restrict__ out, int n4){
  int i = blockIdx.x * 256 + threadIdx.x;
  if (i < n4){
    float4 v = ((const float4*)in)[i];
    uint2 o; o.x = pack2(v.x, v.y); o.y = pack2(v.z, v.w);
    ((uint2*)out)[i] = o;
  }
}

// ---------------- LayerNorm (fp32 in, bf16 out) ----------------
__global__ __launch_bounds__(256) void ln_kernel(
    const float* __restrict__ x, const float* __restrict__ g,
    const float* __restrict__ b, u16* __restrict__ out, int ntok)
{
  int wave = threadIdx.x >> 6, lane = threadIdx.x & 63;
  for (long t = blockIdx.x * 4 + wave; t < ntok; t += (long)gridDim.x * 4){
    const float* xr = x + t * CDIM;
    float v[6]; float s = 0.f, ss = 0.f;
    #pragma unroll
    for (int j = 0; j < 6; ++j){ v[j] = xr[j*64 + lane]; s += v[j]; ss += v[j]*v[j]; }
    #pragma unroll
    for (int o = 32; o >= 1; o >>= 1){ s += __shfl_xor(s, o); ss += __shfl_xor(ss, o); }
    float mean = s * (1.f/384.f);
    float var  = ss * (1.f/384.f) - mean*mean;
    float rs   = rsqrtf(var + 1e-5f);
    #pragma unroll
    for (int j = 0; j < 6; ++j){
      int c = j*64 + lane;
      out[t*CDIM + c] = f2b((v[j] - mean) * rs * g[c] + b[c]);
    }
  }
}

// ---------------- GEMM out[m,n] = sum_k A[m,k]*W[n,k] (+bias, epilogue) ----
// 2-phase prefetch (T3-min template): double LDS buffer, STAGE(next) issued
// before compute(cur), one raw barrier + vmcnt(0) per K-step AFTER the MFMAs.
// 16B-chunk XOR swizzle (col4 ^= row&3) on stage-source + read (rule #21:
// linear LDS dest via global_load_lds, inverse-permuted global source).
// EPI 0: bf16 store (bias)   1: bf16 store (bias+exact gelu)   2: f32 store (bias + resid)
template<int EPI>
__global__ __launch_bounds__(256, 2) void gemm_bt(
    const u16* __restrict__ A, const u16* __restrict__ Wt,
    const float* __restrict__ bias, const float* __restrict__ resid,
    void* __restrict__ outp, int M, int N, int K)
{
  __shared__ __align__(16) u16 lA[2][128*32];
  __shared__ __align__(16) u16 lB[2][128*32];
  const int tid  = threadIdx.x;
  const int wave = tid >> 6, lane = tid & 63;
  const int bn = blockIdx.x, bm = blockIdx.y;   // bn fastest: A-tile L2 reuse
  const int wr = wave >> 1, wc = wave & 1;
  const int l15 = lane & 15, l4 = lane >> 4;
  const int srow = tid >> 2, sch = tid & 3;

  f32x4 acc[4][4] = {};

  auto STAGE = [&](int buf, int kt){
    #pragma unroll
    for (int it = 0; it < 2; ++it){
      int row = it*64 + srow;
      int chs = sch ^ (row & 3);                 // pre-swizzled source chunk
      const u16* ga = A  + (size_t)(bm*128 + row) * K + kt + chs*8;
      const u16* gb = Wt + (size_t)(bn*128 + row) * K + kt + chs*8;
      gload_lds16(ga, &lA[buf][(it*256 + wave*64) * 8]);
      gload_lds16(gb, &lB[buf][(it*256 + wave*64) * 8]);
    }
  };

  const int NK = K >> 5;
  STAGE(0, 0);
  asm volatile("s_waitcnt vmcnt(0)" ::: "memory");
  __builtin_amdgcn_s_barrier();

  int cur = 0;
  for (int ki = 0; ki < NK; ++ki){
    if (ki + 1 < NK) STAGE(cur ^ 1, (ki + 1) * 32);
    bf16x8 af[4], bfr[4];
    const int rc = (l4 ^ (l15 & 3)) * 8;         // swizzled 16B chunk within row
    #pragma unroll
    for (int mi = 0; mi < 4; ++mi)
      af[mi] = *(const bf16x8*)&lA[cur][(wr*64 + mi*16 + l15)*32 + rc];
    #pragma unroll
    for (int ni = 0; ni < 4; ++ni)
      bfr[ni] = *(const bf16x8*)&lB[cur][(wc*64 + ni*16 + l15)*32 + rc];
    #pragma unroll
    for (int mi = 0; mi < 4; ++mi)
      #pragma unroll
      for (int ni = 0; ni < 4; ++ni)
        acc[mi][ni] = __builtin_amdgcn_mfma_f32_16x16x32_bf16(af[mi], bfr[ni], acc[mi][ni], 0, 0, 0);
    asm volatile("s_waitcnt vmcnt(0)" ::: "memory");
    __builtin_amdgcn_s_barrier();
    cur ^= 1;
  }

  #pragma unroll
  for (int ni = 0; ni < 4; ++ni){
    int col = bn*128 + wc*64 + ni*16 + l15;
    float bb = bias[col];
    #pragma unroll
    for (int mi = 0; mi < 4; ++mi){
      int row0 = bm*128 + wr*64 + mi*16 + l4*4;
      #pragma unroll
      for (int r = 0; r < 4; ++r){
        long off = (long)(row0 + r) * N + col;
        float v = acc[mi][ni][r] + bb;
        if (EPI == 0){
          ((u16*)outp)[off] = f2b(v);
        } else if (EPI == 1){
          ((u16*)outp)[off] = f2b(0.5f * v * (1.f + erff(v * 0.70710678118654752f)));
        } else {
          ((float*)outp)[off] = resid[off] + v;
        }
      }
    }
  }
}

// ---------------- bias table: btbl[h][q][l15*4+ni] = rpb[ridx[q][key]][h],
//                  key = ni*16+l15; -1e9 for q>=49 or key>=49 (padding mask)
__global__ void build_btbl(const float* __restrict__ rpb, const int* __restrict__ ridx,
                           float* __restrict__ btbl){
  int q = blockIdx.x & 63, h = blockIdx.x >> 6;
  int l = threadIdx.x;
  float v = -1e9f;
  if (q < 49){
    int key = (l & 3) * 16 + (l >> 2);
    if (key < 49) v = rpb[ridx[q*49 + key] * 12 + h];
  }
  btbl[(h*64 + q)*64 + l] = v;
}

// ---------------- MFMA windowed attention: one wave = one (window, head) ----
template<int SHIFT>
__global__ __launch_bounds__(64) void attn_mfma(
    const u16* __restrict__ qkv,     // [M_TOK][1152] bf16
    const float* __restrict__ btbl,  // [12][64][64] f32 (this block's table)
    u16* __restrict__ attn_out)      // [M_TOK][384] bf16
{
  __shared__ __align__(16) u16 p_lds[64*72];   // P[q][m] bf16, stride 72
  __shared__ __align__(16) u16 vt_lds[32*72];  // V^T[d][m] bf16, stride 72
  __shared__ int tok_lds[64];
  __shared__ int rid_lds[64];

  const int bid = blockIdx.x;
  const int h   = bid % 12;
  const int win = bid / 12;
  const int b   = win >> 6, wl = win & 63;
  const int wy  = wl >> 3,  wx = wl & 7;
  const int lane = threadIdx.x;
  const int l15 = lane & 15, l4 = lane >> 4;

  auto tokof = [&](int n)->int{
    int r = (n * 9363) >> 16;      // n/7 for n<=48
    int c = n - r * 7;
    int hh = wy*7 + r + SHIFT; if (hh >= 56) hh -= 56;
    int ww = wx*7 + c + SHIFT; if (ww >= 56) ww -= 56;
    return b*3136 + hh*56 + ww;
  };

  // ---- staging: V^T (zero-padded cols >=49), token table, region ids ----
  {
    const int n  = lane;
    const int nc = n < 49 ? n : 48;
    const int t  = tokof(nc);
    tok_lds[n] = t;
    if (SHIFT){
      int r = (nc * 9363) >> 16, c = nc - r*7;
      int gh = wy*7 + r, gw = wx*7 + c;
      int rh = gh <= 48 ? 0 : (gh <= 52 ? 1 : 2);
      int rw = gw <= 48 ? 0 : (gw <= 52 ? 1 : 2);
      rid_lds[n] = rh*3 + rw;
    }
    const uint4* vp = (const uint4*)(qkv + (size_t)t*1152 + 768 + h*32);
    u32 w[16];
    #pragma unroll
    for (int j4 = 0; j4 < 4; ++j4){
      uint4 u = vp[j4];
      w[j4*4+0]=u.x; w[j4*4+1]=u.y; w[j4*4+2]=u.z; w[j4*4+3]=u.w;
    }
    if (n >= 49){
      #pragma unroll
      for (int j = 0; j < 16; ++j) w[j] = 0;
    }
    #pragma unroll
    for (int j = 0; j < 16; ++j){
      vt_lds[(2*j  )*72 + n] = (u16)(w[j] & 0xffffu);
      vt_lds[(2*j+1)*72 + n] = (u16)(w[j] >> 16);
    }
  }

  // ---- QK^T fragments directly from global ----
  bf16x8 qa[4], kb[4];
  #pragma unroll
  for (int mi = 0; mi < 4; ++mi){
    int row = mi*16 + l15; int t = tokof(row < 49 ? row : 48);
    qa[mi] = *(const bf16x8*)(qkv + (size_t)t*1152 + h*32 + l4*8);
  }
  #pragma unroll
  for (int ni = 0; ni < 4; ++ni){
    int row = ni*16 + l15; int t = tokof(row < 49 ? row : 48);
    kb[ni] = *(const bf16x8*)(qkv + (size_t)t*1152 + 384 + h*32 + l4*8);
  }
  f32x4 s[4][4] = {};
  #pragma unroll
  for (int mi = 0; mi < 4; ++mi)
    #pragma unroll
    for (int ni = 0; ni < 4; ++ni)
      s[mi][ni] = __builtin_amdgcn_mfma_f32_16x16x32_bf16(qa[mi], kb[ni], s[mi][ni], 0, 0, 0);

  __syncthreads();   // staging (V^T / tok / rid) complete

  int rid_k[4];
  if (SHIFT){
    #pragma unroll
    for (int ni = 0; ni < 4; ++ni) rid_k[ni] = rid_lds[ni*16 + l15];
  }

  // ---- scale + bias + mask, row softmax in-register ----
  const float* bt = btbl + h*4096;
  float den[4][4];
  #pragma unroll
  for (int mi = 0; mi < 4; ++mi){
    #pragma unroll
    for (int r = 0; r < 4; ++r){
      int q = mi*16 + l4*4 + r;
      f32x4 bq = *(const f32x4*)(bt + q*64 + l15*4);
      int ridq = 0;
      if (SHIFT) ridq = rid_lds[q];
      #pragma unroll
      for (int ni = 0; ni < 4; ++ni){
        float v = s[mi][ni][r] * 0.17677669529663687f + bq[ni];
        if (SHIFT) v += (ridq == rid_k[ni]) ? 0.f : -100.f;
        s[mi][ni][r] = v;
      }
      float m0 = fmaxf(fmaxf(s[mi][0][r], s[mi][1][r]), fmaxf(s[mi][2][r], s[mi][3][r]));
      #pragma unroll
      for (int o = 1; o <= 8; o <<= 1) m0 = fmaxf(m0, __shfl_xor(m0, o));
      float d0 = 0.f;
      #pragma unroll
      for (int ni = 0; ni < 4; ++ni){
        float e = __expf(s[mi][ni][r] - m0);
        s[mi][ni][r] = e; d0 += e;
      }
      #pragma unroll
      for (int o = 1; o <= 8; o <<= 1) d0 += __shfl_xor(d0, o);
      den[mi][r] = d0;
    }
  }

  // ---- pack P to LDS (bf16, stride 72) ----
  #pragma unroll
  for (int mi = 0; mi < 4; ++mi)
    #pragma unroll
    for (int r = 0; r < 4; ++r){
      int q = mi*16 + l4*4 + r;
      #pragma unroll
      for (int ni = 0; ni < 4; ++ni)
        p_lds[q*72 + ni*16 + l15] = f2b(s[mi][ni][r]);
    }

  __syncthreads();   // P writes complete

  // ---- PV via MFMA: O[q][d] = sum_m P[q][m] * VT[d][m] ----
  f32x4 o2[4][2] = {};
  #pragma unroll
  for (int ks = 0; ks < 2; ++ks){
    bf16x8 vb[2];
    #pragma unroll
    for (int ni = 0; ni < 2; ++ni)
      vb[ni] = *(const bf16x8*)&vt_lds[(ni*16 + l15)*72 + ks*32 + l4*8];
    #pragma unroll
    for (int mi = 0; mi < 4; ++mi){
      bf16x8 pa = *(const bf16x8*)&p_lds[(mi*16 + l15)*72 + ks*32 + l4*8];
      #pragma unroll
      for (int ni = 0; ni < 2; ++ni)
        o2[mi][ni] = __builtin_amdgcn_mfma_f32_16x16x32_bf16(pa, vb[ni], o2[mi][ni], 0, 0, 0);
    }
  }

  // ---- scaled store (only valid query rows) ----
  #pragma unroll
  for (int mi = 0; mi < 4; ++mi){
    #pragma unroll
    for (int r = 0; r < 4; ++r){
      int q = mi*16 + l4*4 + r;
      if (q < 49){
        float inv = 1.f / den[mi][r];
        long t = tok_lds[q];
        #pragma unroll
        for (int ni = 0; ni < 2; ++ni){
          int d = ni*16 + l15;
          attn_out[t*384 + h*32 + d] = f2b(o2[mi][ni][r] * inv);
        }
      }
    }
  }
}

extern "C" void kernel_launch(void* const* d_in, const int* in_sizes, int n_in,
                              void* d_out, int out_size, void* d_ws, size_t ws_size,
                              hipStream_t stream)
{
  const float* x_in   = (const float*)d_in[0];
  const int*   relidx = (const int*)d_in[2];
  const float* n1g    = (const float*)d_in[3];
  const float* n1b    = (const float*)d_in[4];
  const float* qkvw   = (const float*)d_in[5];
  const float* qkvb   = (const float*)d_in[6];
  const float* rpb    = (const float*)d_in[7];
  const float* pw     = (const float*)d_in[8];
  const float* pb     = (const float*)d_in[9];
  const float* n2g    = (const float*)d_in[10];
  const float* n2b    = (const float*)d_in[11];
  const float* f1w    = (const float*)d_in[12];
  const float* f1b    = (const float*)d_in[13];
  const float* f2w    = (const float*)d_in[14];
  const float* f2bb   = (const float*)d_in[15];
  float* xout = (float*)d_out;

  char* ws = (char*)d_ws;
  u16* wqkv  = (u16*)ws; ws += (size_t)2*1152*384*2;
  u16* wproj = (u16*)ws; ws += (size_t)2*384*384*2;
  u16* wfc1  = (u16*)ws; ws += (size_t)2*1536*384*2;
  u16* wfc2  = (u16*)ws; ws += (size_t)2*384*1536*2;
  u16* bufA  = (u16*)ws; ws += (size_t)M_TOK*1536*2;   // qkv (1152) / h (1536)
  u16* bufB  = (u16*)ws; ws += (size_t)M_TOK*384*2;    // xn / attn_out / h_in
  float* btbl = (float*)(bufA + (size_t)M_TOK*1152);   // tail of bufA during attn

  // convert weights to bf16
  {
    int n;
    n = 2*1152*384;  cvtw<<<dim3((n/4+255)/256), dim3(256), 0, stream>>>(qkvw, wqkv, n/4);
    n = 2*384*384;   cvtw<<<dim3((n/4+255)/256), dim3(256), 0, stream>>>(pw,   wproj, n/4);
    n = 2*1536*384;  cvtw<<<dim3((n/4+255)/256), dim3(256), 0, stream>>>(f1w,  wfc1, n/4);
    n = 2*384*1536;  cvtw<<<dim3((n/4+255)/256), dim3(256), 0, stream>>>(f2w,  wfc2, n/4);
  }

  for (int i = 0; i < 2; ++i){
    const float* xi = (i == 0) ? x_in : xout;
    // LN1 -> bufB (bf16)
    ln_kernel<<<dim3(2048), dim3(256), 0, stream>>>(xi, n1g + i*384, n1b + i*384, bufB, M_TOK);
    // QKV: bufB @ wqkv^T -> bufA  [M,1152]
    gemm_bt<0><<<dim3(9, 392), dim3(256), 0, stream>>>(
        bufB, wqkv + (size_t)i*1152*384, qkvb + i*1152, nullptr, bufA, M_TOK, 1152, 384);
    // bias table for this block
    build_btbl<<<dim3(768), dim3(64), 0, stream>>>(rpb + (size_t)i*169*12, relidx, btbl);
    // attention: bufA -> bufB [M,384]
    if (i == 0)
      attn_mfma<0><<<dim3(12288), dim3(64), 0, stream>>>(bufA, btbl, bufB);
    else
      attn_mfma<3><<<dim3(12288), dim3(64), 0, stream>>>(bufA, btbl, bufB);
    // proj + residual: xout = xi + bufB @ wproj^T + pb   [M,384] f32
    gemm_bt<2><<<dim3(3, 392), dim3(256), 0, stream>>>(
        bufB, wproj + (size_t)i*384*384, pb + i*384, xi, xout, M_TOK, 384, 384);
    // LN2 -> bufB (bf16)
    ln_kernel<<<dim3(2048), dim3(256), 0, stream>>>(xout, n2g + i*384, n2b + i*384, bufB, M_TOK);
    // FC1 + gelu: bufB @ wfc1^T -> bufA [M,1536] bf16
    gemm_bt<1><<<dim3(12, 392), dim3(256), 0, stream>>>(
        bufB, wfc1 + (size_t)i*1536*384, f1b + i*1536, nullptr, bufA, M_TOK, 1536, 384);
    // FC2 + residual: xout += bufA @ wfc2^T + f2b  [M,384] f32
    gemm_bt<2><<<dim3(3, 392), dim3(256), 0, stream>>>(
        bufA, wfc2 + (size_t)i*384*1536, f2bb + i*384, xout, xout, M_TOK, 384, 1536);
  }
  (void)in_sizes; (void)n_in; (void)out_size; (void)ws_size;
}

// Round 4
// 1051.872 us; speedup vs baseline: 1.5244x; 1.0074x over previous
//
#include <hip/hip_runtime.h>
#include <math.h>

typedef unsigned short u16;
typedef unsigned int   u32;
typedef __attribute__((ext_vector_type(4))) float f32x4;
typedef __attribute__((ext_vector_type(8))) short bf16x8;

#define M_TOK 50176
#define CDIM  384

__device__ __forceinline__ u16 f2b(float f){
  union { float f; u32 u; } v; v.f = f;
  u32 r = v.u + 0x7fffu + ((v.u >> 16) & 1u);
  return (u16)(r >> 16);
}
__device__ __forceinline__ u32 pack2(float a, float b){
  return (u32)f2b(a) | ((u32)f2b(b) << 16);
}

__device__ __forceinline__ void gload_lds16(const u16* g, u16* l){
  __builtin_amdgcn_global_load_lds((const __attribute__((address_space(1))) u32*)g,
                                   (__attribute__((address_space(3))) u32*)l, 16, 0, 0);
}

// ---------------- weight convert f32 -> bf16 ----------------
__global__ void cvtw(const float* __restrict__ in, u16* __restrict__ out, int n4){
  int i = blockIdx.x * 256 + threadIdx.x;
  if (i < n4){
    float4 v = ((const float4*)in)[i];
    uint2 o; o.x = pack2(v.x, v.y); o.y = pack2(v.z, v.w);
    ((uint2*)out)[i] = o;
  }
}

// ---------------- LayerNorm (fp32 in, bf16 out) ----------------
__global__ __launch_bounds__(256) void ln_kernel(
    const float* __restrict__ x, const float* __restrict__ g,
    const float* __restrict__ b, u16* __restrict__ out, int ntok)
{
  int wave = threadIdx.x >> 6, lane = threadIdx.x & 63;
  for (long t = blockIdx.x * 4 + wave; t < ntok; t += (long)gridDim.x * 4){
    const float* xr = x + t * CDIM;
    float v[6]; float s = 0.f, ss = 0.f;
    #pragma unroll
    for (int j = 0; j < 6; ++j){ v[j] = xr[j*64 + lane]; s += v[j]; ss += v[j]*v[j]; }
    #pragma unroll
    for (int o = 32; o >= 1; o >>= 1){ s += __shfl_xor(s, o); ss += __shfl_xor(ss, o); }
    float mean = s * (1.f/384.f);
    float var  = ss * (1.f/384.f) - mean*mean;
    float rs   = rsqrtf(var + 1e-5f);
    #pragma unroll
    for (int j = 0; j < 6; ++j){
      int c = j*64 + lane;
      out[t*CDIM + c] = f2b((v[j] - mean) * rs * g[c] + b[c]);
    }
  }
}

// ---------------- GEMM out[m,n] = sum_k A[m,k]*W[n,k] (+bias, epilogue) ----
// Double-buffered, counted-vmcnt pipeline (T3+T4):
//   STAGE(next) -> vmcnt(4) [drain prev STAGE only] -> barrier ->
//   ds_read(cur)+MFMA -> barrier  (2nd barrier = WAR guard for next STAGE)
// LDS swizzle: chunk ^= (row>>1)&3 on stage-source AND read (rule #21) ->
// 2-way bank aliasing (free, m136).
// EPI 0: bf16 (bias)   1: bf16 (bias+exact gelu)   2: f32 (bias + resid)
template<int EPI>
__global__ __launch_bounds__(256, 4) void gemm_bt(
    const u16* __restrict__ A, const u16* __restrict__ Wt,
    const float* __restrict__ bias, const float* __restrict__ resid,
    void* __restrict__ outp, int M, int N, int K)
{
  __shared__ __align__(16) u16 lA[2][128*32];
  __shared__ __align__(16) u16 lB[2][128*32];
  const int tid  = threadIdx.x;
  const int wave = tid >> 6, lane = tid & 63;
  const int bn = blockIdx.x, bm = blockIdx.y;   // bn fastest: A-tile L2 reuse
  const int wr = wave >> 1, wc = wave & 1;
  const int l15 = lane & 15, l4 = lane >> 4;
  const int srow = tid >> 2, sch = tid & 3;

  f32x4 acc[4][4] = {};

  auto STAGE = [&](int buf, int kt){
    #pragma unroll
    for (int it = 0; it < 2; ++it){
      int row = it*64 + srow;
      int chs = sch ^ ((srow >> 1) & 3);         // pre-swizzled source chunk
      const u16* ga = A  + (size_t)(bm*128 + row) * K + kt + chs*8;
      const u16* gb = Wt + (size_t)(bn*128 + row) * K + kt + chs*8;
      gload_lds16(ga, &lA[buf][(it*256 + wave*64) * 8]);
      gload_lds16(gb, &lB[buf][(it*256 + wave*64) * 8]);
    }
  };

  const int NK = K >> 5;
  STAGE(0, 0);

  int cur = 0;
  for (int ki = 0; ki < NK; ++ki){
    if (ki + 1 < NK){
      STAGE(cur ^ 1, (ki + 1) * 32);
      asm volatile("s_waitcnt vmcnt(4)" ::: "memory");  // prev STAGE done; new 4 in flight
    } else {
      asm volatile("s_waitcnt vmcnt(0)" ::: "memory");
    }
    __builtin_amdgcn_s_barrier();                       // buf[cur] visible to all
    bf16x8 af[4], bfr[4];
    const int rc = (l4 ^ ((l15 >> 1) & 3)) * 8;         // swizzled 16B chunk
    #pragma unroll
    for (int mi = 0; mi < 4; ++mi)
      af[mi] = *(const bf16x8*)&lA[cur][(wr*64 + mi*16 + l15)*32 + rc];
    #pragma unroll
    for (int ni = 0; ni < 4; ++ni)
      bfr[ni] = *(const bf16x8*)&lB[cur][(wc*64 + ni*16 + l15)*32 + rc];
    #pragma unroll
    for (int mi = 0; mi < 4; ++mi)
      #pragma unroll
      for (int ni = 0; ni < 4; ++ni)
        acc[mi][ni] = __builtin_amdgcn_mfma_f32_16x16x32_bf16(af[mi], bfr[ni], acc[mi][ni], 0, 0, 0);
    __builtin_amdgcn_s_barrier();                       // reads of buf[cur] done (WAR)
    cur ^= 1;
  }

  #pragma unroll
  for (int ni = 0; ni < 4; ++ni){
    int col = bn*128 + wc*64 + ni*16 + l15;
    float bb = bias[col];
    #pragma unroll
    for (int mi = 0; mi < 4; ++mi){
      int row0 = bm*128 + wr*64 + mi*16 + l4*4;
      #pragma unroll
      for (int r = 0; r < 4; ++r){
        long off = (long)(row0 + r) * N + col;
        float v = acc[mi][ni][r] + bb;
        if (EPI == 0){
          ((u16*)outp)[off] = f2b(v);
        } else if (EPI == 1){
          ((u16*)outp)[off] = f2b(0.5f * v * (1.f + erff(v * 0.70710678118654752f)));
        } else {
          ((float*)outp)[off] = resid[off] + v;
        }
      }
    }
  }
}

// ---------------- bias table: btbl[h][q][l15*4+ni] = rpb[ridx[q][key]][h],
//                  key = ni*16+l15; -1e9 for q>=49 or key>=49 (padding mask)
__global__ void build_btbl(const float* __restrict__ rpb, const int* __restrict__ ridx,
                           float* __restrict__ btbl){
  int q = blockIdx.x & 63, h = blockIdx.x >> 6;
  int l = threadIdx.x;
  float v = -1e9f;
  if (q < 49){
    int key = (l & 3) * 16 + (l >> 2);
    if (key < 49) v = rpb[ridx[q*49 + key] * 12 + h];
  }
  btbl[(h*64 + q)*64 + l] = v;
}

// ---------------- MFMA windowed attention: one wave = one (window, head) ----
template<int SHIFT>
__global__ __launch_bounds__(64) void attn_mfma(
    const u16* __restrict__ qkv,     // [M_TOK][1152] bf16
    const float* __restrict__ btbl,  // [12][64][64] f32 (this block's table)
    u16* __restrict__ attn_out)      // [M_TOK][384] bf16
{
  __shared__ __align__(16) u16 p_lds[64*72];   // P[q][m] bf16, stride 72
  __shared__ __align__(16) u16 vt_lds[32*72];  // V^T[d][m] bf16, stride 72
  __shared__ int tok_lds[64];
  __shared__ int rid_lds[64];

  const int bid = blockIdx.x;
  const int h   = bid % 12;
  const int win = bid / 12;
  const int b   = win >> 6, wl = win & 63;
  const int wy  = wl >> 3,  wx = wl & 7;
  const int lane = threadIdx.x;
  const int l15 = lane & 15, l4 = lane >> 4;

  auto tokof = [&](int n)->int{
    int r = (n * 9363) >> 16;      // n/7 for n<=48
    int c = n - r * 7;
    int hh = wy*7 + r + SHIFT; if (hh >= 56) hh -= 56;
    int ww = wx*7 + c + SHIFT; if (ww >= 56) ww -= 56;
    return b*3136 + hh*56 + ww;
  };

  // ---- staging: V^T (zero-padded cols >=49), token table, region ids ----
  {
    const int n  = lane;
    const int nc = n < 49 ? n : 48;
    const int t  = tokof(nc);
    tok_lds[n] = t;
    if (SHIFT){
      int r = (nc * 9363) >> 16, c = nc - r*7;
      int gh = wy*7 + r, gw = wx*7 + c;
      int rh = gh <= 48 ? 0 : (gh <= 52 ? 1 : 2);
      int rw = gw <= 48 ? 0 : (gw <= 52 ? 1 : 2);
      rid_lds[n] = rh*3 + rw;
    }
    const uint4* vp = (const uint4*)(qkv + (size_t)t*1152 + 768 + h*32);
    u32 w[16];
    #pragma unroll
    for (int j4 = 0; j4 < 4; ++j4){
      uint4 u = vp[j4];
      w[j4*4+0]=u.x; w[j4*4+1]=u.y; w[j4*4+2]=u.z; w[j4*4+3]=u.w;
    }
    if (n >= 49){
      #pragma unroll
      for (int j = 0; j < 16; ++j) w[j] = 0;
    }
    #pragma unroll
    for (int j = 0; j < 16; ++j){
      vt_lds[(2*j  )*72 + n] = (u16)(w[j] & 0xffffu);
      vt_lds[(2*j+1)*72 + n] = (u16)(w[j] >> 16);
    }
  }

  // ---- QK^T fragments directly from global ----
  bf16x8 qa[4], kb[4];
  #pragma unroll
  for (int mi = 0; mi < 4; ++mi){
    int row = mi*16 + l15; int t = tokof(row < 49 ? row : 48);
    qa[mi] = *(const bf16x8*)(qkv + (size_t)t*1152 + h*32 + l4*8);
  }
  #pragma unroll
  for (int ni = 0; ni < 4; ++ni){
    int row = ni*16 + l15; int t = tokof(row < 49 ? row : 48);
    kb[ni] = *(const bf16x8*)(qkv + (size_t)t*1152 + 384 + h*32 + l4*8);
  }
  f32x4 s[4][4] = {};
  #pragma unroll
  for (int mi = 0; mi < 4; ++mi)
    #pragma unroll
    for (int ni = 0; ni < 4; ++ni)
      s[mi][ni] = __builtin_amdgcn_mfma_f32_16x16x32_bf16(qa[mi], kb[ni], s[mi][ni], 0, 0, 0);

  __syncthreads();   // staging (V^T / tok / rid) complete

  int rid_k[4];
  if (SHIFT){
    #pragma unroll
    for (int ni = 0; ni < 4; ++ni) rid_k[ni] = rid_lds[ni*16 + l15];
  }

  // ---- scale + bias + mask, row softmax in-register ----
  const float* bt = btbl + h*4096;
  float den[4][4];
  #pragma unroll
  for (int mi = 0; mi < 4; ++mi){
    #pragma unroll
    for (int r = 0; r < 4; ++r){
      int q = mi*16 + l4*4 + r;
      f32x4 bq = *(const f32x4*)(bt + q*64 + l15*4);
      int ridq = 0;
      if (SHIFT) ridq = rid_lds[q];
      #pragma unroll
      for (int ni = 0; ni < 4; ++ni){
        float v = s[mi][ni][r] * 0.17677669529663687f + bq[ni];
        if (SHIFT) v += (ridq == rid_k[ni]) ? 0.f : -100.f;
        s[mi][ni][r] = v;
      }
      float m0 = fmaxf(fmaxf(s[mi][0][r], s[mi][1][r]), fmaxf(s[mi][2][r], s[mi][3][r]));
      #pragma unroll
      for (int o = 1; o <= 8; o <<= 1) m0 = fmaxf(m0, __shfl_xor(m0, o));
      float d0 = 0.f;
      #pragma unroll
      for (int ni = 0; ni < 4; ++ni){
        float e = __expf(s[mi][ni][r] - m0);
        s[mi][ni][r] = e; d0 += e;
      }
      #pragma unroll
      for (int o = 1; o <= 8; o <<= 1) d0 += __shfl_xor(d0, o);
      den[mi][r] = d0;
    }
  }

  // ---- pack P to LDS (bf16, stride 72) ----
  #pragma unroll
  for (int mi = 0; mi < 4; ++mi)
    #pragma unroll
    for (int r = 0; r < 4; ++r){
      int q = mi*16 + l4*4 + r;
      #pragma unroll
      for (int ni = 0; ni < 4; ++ni)
        p_lds[q*72 + ni*16 + l15] = f2b(s[mi][ni][r]);
    }

  __syncthreads();   // P writes complete

  // ---- PV via MFMA: O[q][d] = sum_m P[q][m] * VT[d][m] ----
  f32x4 o2[4][2] = {};
  #pragma unroll
  for (int ks = 0; ks < 2; ++ks){
    bf16x8 vb[2];
    #pragma unroll
    for (int ni = 0; ni < 2; ++ni)
      vb[ni] = *(const bf16x8*)&vt_lds[(ni*16 + l15)*72 + ks*32 + l4*8];
    #pragma unroll
    for (int mi = 0; mi < 4; ++mi){
      bf16x8 pa = *(const bf16x8*)&p_lds[(mi*16 + l15)*72 + ks*32 + l4*8];
      #pragma unroll
      for (int ni = 0; ni < 2; ++ni)
        o2[mi][ni] = __builtin_amdgcn_mfma_f32_16x16x32_bf16(pa, vb[ni], o2[mi][ni], 0, 0, 0);
    }
  }

  // ---- scaled store (only valid query rows) ----
  #pragma unroll
  for (int mi = 0; mi < 4; ++mi){
    #pragma unroll
    for (int r = 0; r < 4; ++r){
      int q = mi*16 + l4*4 + r;
      if (q < 49){
        float inv = 1.f / den[mi][r];
        long t = tok_lds[q];
        #pragma unroll
        for (int ni = 0; ni < 2; ++ni){
          int d = ni*16 + l15;
          attn_out[t*384 + h*32 + d] = f2b(o2[mi][ni][r] * inv);
        }
      }
    }
  }
}

extern "C" void kernel_launch(void* const* d_in, const int* in_sizes, int n_in,
                              void* d_out, int out_size, void* d_ws, size_t ws_size,
                              hipStream_t stream)
{
  const float* x_in   = (const float*)d_in[0];
  const int*   relidx = (const int*)d_in[2];
  const float* n1g    = (const float*)d_in[3];
  const float* n1b    = (const float*)d_in[4];
  const float* qkvw   = (const float*)d_in[5];
  const float* qkvb   = (const float*)d_in[6];
  const float* rpb    = (const float*)d_in[7];
  const float* pw     = (const float*)d_in[8];
  const float* pb     = (const float*)d_in[9];
  const float* n2g    = (const float*)d_in[10];
  const float* n2b    = (const float*)d_in[11];
  const float* f1w    = (const float*)d_in[12];
  const float* f1b    = (const float*)d_in[13];
  const float* f2w    = (const float*)d_in[14];
  const float* f2bb   = (const float*)d_in[15];
  float* xout = (float*)d_out;

  char* ws = (char*)d_ws;
  u16* wqkv  = (u16*)ws; ws += (size_t)2*1152*384*2;
  u16* wproj = (u16*)ws; ws += (size_t)2*384*384*2;
  u16* wfc1  = (u16*)ws; ws += (size_t)2*1536*384*2;
  u16* wfc2  = (u16*)ws; ws += (size_t)2*384*1536*2;
  u16* bufA  = (u16*)ws; ws += (size_t)M_TOK*1536*2;   // qkv (1152) / h (1536)
  u16* bufB  = (u16*)ws; ws += (size_t)M_TOK*384*2;    // xn / attn_out / h_in
  float* btbl = (float*)(bufA + (size_t)M_TOK*1152);   // tail of bufA during attn

  // convert weights to bf16
  {
    int n;
    n = 2*1152*384;  cvtw<<<dim3((n/4+255)/256), dim3(256), 0, stream>>>(qkvw, wqkv, n/4);
    n = 2*384*384;   cvtw<<<dim3((n/4+255)/256), dim3(256), 0, stream>>>(pw,   wproj, n/4);
    n = 2*1536*384;  cvtw<<<dim3((n/4+255)/256), dim3(256), 0, stream>>>(f1w,  wfc1, n/4);
    n = 2*384*1536;  cvtw<<<dim3((n/4+255)/256), dim3(256), 0, stream>>>(f2w,  wfc2, n/4);
  }

  for (int i = 0; i < 2; ++i){
    const float* xi = (i == 0) ? x_in : xout;
    // LN1 -> bufB (bf16)
    ln_kernel<<<dim3(2048), dim3(256), 0, stream>>>(xi, n1g + i*384, n1b + i*384, bufB, M_TOK);
    // QKV: bufB @ wqkv^T -> bufA  [M,1152]
    gemm_bt<0><<<dim3(9, 392), dim3(256), 0, stream>>>(
        bufB, wqkv + (size_t)i*1152*384, qkvb + i*1152, nullptr, bufA, M_TOK, 1152, 384);
    // bias table for this block
    build_btbl<<<dim3(768), dim3(64), 0, stream>>>(rpb + (size_t)i*169*12, relidx, btbl);
    // attention: bufA -> bufB [M,384]
    if (i == 0)
      attn_mfma<0><<<dim3(12288), dim3(64), 0, stream>>>(bufA, btbl, bufB);
    else
      attn_mfma<3><<<dim3(12288), dim3(64), 0, stream>>>(bufA, btbl, bufB);
    // proj + residual: xout = xi + bufB @ wproj^T + pb   [M,384] f32
    gemm_bt<2><<<dim3(3, 392), dim3(256), 0, stream>>>(
        bufB, wproj + (size_t)i*384*384, pb + i*384, xi, xout, M_TOK, 384, 384);
    // LN2 -> bufB (bf16)
    ln_kernel<<<dim3(2048), dim3(256), 0, stream>>>(xout, n2g + i*384, n2b + i*384, bufB, M_TOK);
    // FC1 + gelu: bufB @ wfc1^T -> bufA [M,1536] bf16
    gemm_bt<1><<<dim3(12, 392), dim3(256), 0, stream>>>(
        bufB, wfc1 + (size_t)i*1536*384, f1b + i*1536, nullptr, bufA, M_TOK, 1536, 384);
    // FC2 + residual: xout += bufA @ wfc2^T + f2b  [M,384] f32
    gemm_bt<2><<<dim3(3, 392), dim3(256), 0, stream>>>(
        bufA, wfc2 + (size_t)i*384*1536, f2bb + i*384, xout, xout, M_TOK, 384, 1536);
  }
  (void)in_sizes; (void)n_in; (void)out_size; (void)ws_size;
}

// Round 5
// 967.675 us; speedup vs baseline: 1.6570x; 1.0870x over previous
//
#include <hip/hip_runtime.h>
#include <math.h>

typedef unsigned short u16;
typedef unsigned int   u32;
typedef __attribute__((ext_vector_type(4))) float f32x4;
typedef __attribute__((ext_vector_type(8))) short bf16x8;

#define M_TOK 50176
#define CDIM  384

__device__ __forceinline__ u16 f2b(float f){
  union { float f; u32 u; } v; v.f = f;
  u32 r = v.u + 0x7fffu + ((v.u >> 16) & 1u);
  return (u16)(r >> 16);
}
__device__ __forceinline__ u32 pack2(float a, float b){
  return (u32)f2b(a) | ((u32)f2b(b) << 16);
}

__device__ __forceinline__ void gload_lds16(const u16* g, u16* l){
  __builtin_amdgcn_global_load_lds((const __attribute__((address_space(1))) u32*)g,
                                   (__attribute__((address_space(3))) u32*)l, 16, 0, 0);
}

// ---------------- weight convert f32 -> bf16 ----------------
__global__ void cvtw(const float* __restrict__ in, u16* __restrict__ out, int n4){
  int i = blockIdx.x * 256 + threadIdx.x;
  if (i < n4){
    float4 v = ((const float4*)in)[i];
    uint2 o; o.x = pack2(v.x, v.y); o.y = pack2(v.z, v.w);
    ((uint2*)out)[i] = o;
  }
}

// ---------------- LayerNorm (fp32 in, bf16 out) ----------------
__global__ __launch_bounds__(256) void ln_kernel(
    const float* __restrict__ x, const float* __restrict__ g,
    const float* __restrict__ b, u16* __restrict__ out, int ntok)
{
  int wave = threadIdx.x >> 6, lane = threadIdx.x & 63;
  for (long t = blockIdx.x * 4 + wave; t < ntok; t += (long)gridDim.x * 4){
    const float* xr = x + t * CDIM;
    float v[6]; float s = 0.f, ss = 0.f;
    #pragma unroll
    for (int j = 0; j < 6; ++j){ v[j] = xr[j*64 + lane]; s += v[j]; ss += v[j]*v[j]; }
    #pragma unroll
    for (int o = 32; o >= 1; o >>= 1){ s += __shfl_xor(s, o); ss += __shfl_xor(ss, o); }
    float mean = s * (1.f/384.f);
    float var  = ss * (1.f/384.f) - mean*mean;
    float rs   = rsqrtf(var + 1e-5f);
    #pragma unroll
    for (int j = 0; j < 6; ++j){
      int c = j*64 + lane;
      out[t*CDIM + c] = f2b((v[j] - mean) * rs * g[c] + b[c]);
    }
  }
}

// ---------------- GEMM out[m,n] = sum_k A[m,k]*W[n,k] (+bias, epilogue) ----
// T1: bijective XCD-chunked swizzle on 1-D grid (grid%8==0) so blocks that
//     share an A-panel land on ONE XCD's L2 -> A fetched ~once from HBM.
// T3/T4: double-buffered LDS, counted vmcnt(4), raw barriers.
// LDS swizzle: chunk ^= (row>>1)&3 on stage-source AND read -> 2-way (free).
// bf16 epilogues bounce through LDS (reusing the 32KB staging buffer) for
// full-64B-line global writes.
// EPI 0: bf16 (bias)   1: bf16 (bias+exact gelu)   2: f32 (bias + resid)
template<int EPI>
__global__ __launch_bounds__(256, 4) void gemm_bt(
    const u16* __restrict__ A, const u16* __restrict__ Wt,
    const float* __restrict__ bias, const float* __restrict__ resid,
    void* __restrict__ outp, int M, int N, int K)
{
  __shared__ __align__(16) u16 smem[16384];   // 32 KB: [A0|A1|B0|B1] / epi 128x128
  const int tid  = threadIdx.x;
  const int wave = tid >> 6, lane = tid & 63;
  const int nbn  = N >> 7;
  const int cpx  = gridDim.x >> 3;
  const int sid  = (blockIdx.x & 7) * cpx + (blockIdx.x >> 3);
  const int bm = sid / nbn, bn = sid % nbn;   // bn fastest within an XCD chunk
  const int wr = wave >> 1, wc = wave & 1;
  const int l15 = lane & 15, l4 = lane >> 4;
  const int srow = tid >> 2, sch = tid & 3;

  f32x4 acc[4][4] = {};

  auto STAGE = [&](int buf, int kt){
    u16* lAp = smem + buf*4096;
    u16* lBp = smem + 8192 + buf*4096;
    #pragma unroll
    for (int it = 0; it < 2; ++it){
      int row = it*64 + srow;
      int chs = sch ^ ((srow >> 1) & 3);         // pre-swizzled source chunk
      const u16* ga = A  + (size_t)(bm*128 + row) * K + kt + chs*8;
      const u16* gb = Wt + (size_t)(bn*128 + row) * K + kt + chs*8;
      gload_lds16(ga, &lAp[(it*256 + wave*64) * 8]);
      gload_lds16(gb, &lBp[(it*256 + wave*64) * 8]);
    }
  };

  const int NK = K >> 5;
  STAGE(0, 0);

  int cur = 0;
  for (int ki = 0; ki < NK; ++ki){
    if (ki + 1 < NK){
      STAGE(cur ^ 1, (ki + 1) * 32);
      asm volatile("s_waitcnt vmcnt(4)" ::: "memory");  // prev STAGE done; new 4 in flight
    } else {
      asm volatile("s_waitcnt vmcnt(0)" ::: "memory");
    }
    __builtin_amdgcn_s_barrier();                       // buf[cur] visible to all
    const u16* lAp = smem + cur*4096;
    const u16* lBp = smem + 8192 + cur*4096;
    bf16x8 af[4], bfr[4];
    const int rc = (l4 ^ ((l15 >> 1) & 3)) * 8;         // swizzled 16B chunk
    #pragma unroll
    for (int mi = 0; mi < 4; ++mi)
      af[mi] = *(const bf16x8*)&lAp[(wr*64 + mi*16 + l15)*32 + rc];
    #pragma unroll
    for (int ni = 0; ni < 4; ++ni)
      bfr[ni] = *(const bf16x8*)&lBp[(wc*64 + ni*16 + l15)*32 + rc];
    #pragma unroll
    for (int mi = 0; mi < 4; ++mi)
      #pragma unroll
      for (int ni = 0; ni < 4; ++ni)
        acc[mi][ni] = __builtin_amdgcn_mfma_f32_16x16x32_bf16(af[mi], bfr[ni], acc[mi][ni], 0, 0, 0);
    __builtin_amdgcn_s_barrier();                       // reads of buf[cur] done (WAR)
    cur ^= 1;
  }

  if (EPI == 2){
    // f32 + residual: 16 lanes x 4B = full 64B lines already
    #pragma unroll
    for (int ni = 0; ni < 4; ++ni){
      int col = bn*128 + wc*64 + ni*16 + l15;
      float bb = bias[col];
      #pragma unroll
      for (int mi = 0; mi < 4; ++mi){
        int row0 = bm*128 + wr*64 + mi*16 + l4*4;
        #pragma unroll
        for (int r = 0; r < 4; ++r){
          long off = (long)(row0 + r) * N + col;
          ((float*)outp)[off] = resid[off] + acc[mi][ni][r] + bb;
        }
      }
    }
  } else {
    // bf16: bounce through LDS (XOR col^(l4*16)) -> coalesced u32 row stores
    #pragma unroll
    for (int ni = 0; ni < 4; ++ni){
      int colL = wc*64 + ni*16 + l15;
      float bb = bias[bn*128 + colL];
      int colS = colL ^ (l4*16);
      #pragma unroll
      for (int mi = 0; mi < 4; ++mi){
        int rowL = wr*64 + mi*16 + l4*4;
        #pragma unroll
        for (int r = 0; r < 4; ++r){
          float v = acc[mi][ni][r] + bb;
          if (EPI == 1) v = 0.5f * v * (1.f + erff(v * 0.70710678118654752f));
          smem[(rowL + r)*128 + colS] = f2b(v);
        }
      }
    }
    __syncthreads();
    const u32* eb = (const u32*)smem;
    u32* og = (u32*)outp;
    const int nW = N >> 1;
    #pragma unroll
    for (int it = 0; it < 32; ++it){
      int row = wave*32 + it;
      u32 w = eb[row*64 + (lane ^ (((row >> 2) & 3) * 8))];
      og[(size_t)(bm*128 + row) * nW + bn*64 + lane] = w;
    }
  }
}

// ---------------- bias table: btbl[h][q][l15*4+ni] = rpb[ridx[q][key]][h],
//                  key = ni*16+l15; -1e9 for q>=49 or key>=49 (padding mask)
__global__ void build_btbl(const float* __restrict__ rpb, const int* __restrict__ ridx,
                           float* __restrict__ btbl){
  int q = blockIdx.x & 63, h = blockIdx.x >> 6;
  int l = threadIdx.x;
  float v = -1e9f;
  if (q < 49){
    int key = (l & 3) * 16 + (l >> 2);
    if (key < 49) v = rpb[ridx[q*49 + key] * 12 + h];
  }
  btbl[(h*64 + q)*64 + l] = v;
}

// ---------------- MFMA windowed attention: one wave = one (window, head) ----
template<int SHIFT>
__global__ __launch_bounds__(64) void attn_mfma(
    const u16* __restrict__ qkv,     // [M_TOK][1152] bf16
    const float* __restrict__ btbl,  // [12][64][64] f32 (this block's table)
    u16* __restrict__ attn_out)      // [M_TOK][384] bf16
{
  __shared__ __align__(16) u16 p_lds[64*72];   // P[q][m] bf16, stride 72
  __shared__ __align__(16) u16 vt_lds[32*72];  // V^T[d][m] bf16, stride 72
  __shared__ int tok_lds[64];
  __shared__ int rid_lds[64];

  const int bid = blockIdx.x;
  const int h   = bid % 12;
  const int win = bid / 12;
  const int b   = win >> 6, wl = win & 63;
  const int wy  = wl >> 3,  wx = wl & 7;
  const int lane = threadIdx.x;
  const int l15 = lane & 15, l4 = lane >> 4;

  auto tokof = [&](int n)->int{
    int r = (n * 9363) >> 16;      // n/7 for n<=48
    int c = n - r * 7;
    int hh = wy*7 + r + SHIFT; if (hh >= 56) hh -= 56;
    int ww = wx*7 + c + SHIFT; if (ww >= 56) ww -= 56;
    return b*3136 + hh*56 + ww;
  };

  // ---- staging: V^T (zero-padded cols >=49), token table, region ids ----
  {
    const int n  = lane;
    const int nc = n < 49 ? n : 48;
    const int t  = tokof(nc);
    tok_lds[n] = t;
    if (SHIFT){
      int r = (nc * 9363) >> 16, c = nc - r*7;
      int gh = wy*7 + r, gw = wx*7 + c;
      int rh = gh <= 48 ? 0 : (gh <= 52 ? 1 : 2);
      int rw = gw <= 48 ? 0 : (gw <= 52 ? 1 : 2);
      rid_lds[n] = rh*3 + rw;
    }
    const uint4* vp = (const uint4*)(qkv + (size_t)t*1152 + 768 + h*32);
    u32 w[16];
    #pragma unroll
    for (int j4 = 0; j4 < 4; ++j4){
      uint4 u = vp[j4];
      w[j4*4+0]=u.x; w[j4*4+1]=u.y; w[j4*4+2]=u.z; w[j4*4+3]=u.w;
    }
    if (n >= 49){
      #pragma unroll
      for (int j = 0; j < 16; ++j) w[j] = 0;
    }
    #pragma unroll
    for (int j = 0; j < 16; ++j){
      vt_lds[(2*j  )*72 + n] = (u16)(w[j] & 0xffffu);
      vt_lds[(2*j+1)*72 + n] = (u16)(w[j] >> 16);
    }
  }

  // ---- QK^T fragments directly from global ----
  bf16x8 qa[4], kb[4];
  #pragma unroll
  for (int mi = 0; mi < 4; ++mi){
    int row = mi*16 + l15; int t = tokof(row < 49 ? row : 48);
    qa[mi] = *(const bf16x8*)(qkv + (size_t)t*1152 + h*32 + l4*8);
  }
  #pragma unroll
  for (int ni = 0; ni < 4; ++ni){
    int row = ni*16 + l15; int t = tokof(row < 49 ? row : 48);
    kb[ni] = *(const bf16x8*)(qkv + (size_t)t*1152 + 384 + h*32 + l4*8);
  }
  f32x4 s[4][4] = {};
  #pragma unroll
  for (int mi = 0; mi < 4; ++mi)
    #pragma unroll
    for (int ni = 0; ni < 4; ++ni)
      s[mi][ni] = __builtin_amdgcn_mfma_f32_16x16x32_bf16(qa[mi], kb[ni], s[mi][ni], 0, 0, 0);

  __syncthreads();   // staging (V^T / tok / rid) complete

  int rid_k[4];
  if (SHIFT){
    #pragma unroll
    for (int ni = 0; ni < 4; ++ni) rid_k[ni] = rid_lds[ni*16 + l15];
  }

  // ---- scale + bias + mask, row softmax in-register ----
  const float* bt = btbl + h*4096;
  float den[4][4];
  #pragma unroll
  for (int mi = 0; mi < 4; ++mi){
    #pragma unroll
    for (int r = 0; r < 4; ++r){
      int q = mi*16 + l4*4 + r;
      f32x4 bq = *(const f32x4*)(bt + q*64 + l15*4);
      int ridq = 0;
      if (SHIFT) ridq = rid_lds[q];
      #pragma unroll
      for (int ni = 0; ni < 4; ++ni){
        float v = s[mi][ni][r] * 0.17677669529663687f + bq[ni];
        if (SHIFT) v += (ridq == rid_k[ni]) ? 0.f : -100.f;
        s[mi][ni][r] = v;
      }
      float m0 = fmaxf(fmaxf(s[mi][0][r], s[mi][1][r]), fmaxf(s[mi][2][r], s[mi][3][r]));
      #pragma unroll
      for (int o = 1; o <= 8; o <<= 1) m0 = fmaxf(m0, __shfl_xor(m0, o));
      float d0 = 0.f;
      #pragma unroll
      for (int ni = 0; ni < 4; ++ni){
        float e = __expf(s[mi][ni][r] - m0);
        s[mi][ni][r] = e; d0 += e;
      }
      #pragma unroll
      for (int o = 1; o <= 8; o <<= 1) d0 += __shfl_xor(d0, o);
      den[mi][r] = d0;
    }
  }

  // ---- pack P to LDS (bf16, stride 72) ----
  #pragma unroll
  for (int mi = 0; mi < 4; ++mi)
    #pragma unroll
    for (int r = 0; r < 4; ++r){
      int q = mi*16 + l4*4 + r;
      #pragma unroll
      for (int ni = 0; ni < 4; ++ni)
        p_lds[q*72 + ni*16 + l15] = f2b(s[mi][ni][r]);
    }

  __syncthreads();   // P writes complete

  // ---- PV via MFMA: O[q][d] = sum_m P[q][m] * VT[d][m] ----
  f32x4 o2[4][2] = {};
  #pragma unroll
  for (int ks = 0; ks < 2; ++ks){
    bf16x8 vb[2];
    #pragma unroll
    for (int ni = 0; ni < 2; ++ni)
      vb[ni] = *(const bf16x8*)&vt_lds[(ni*16 + l15)*72 + ks*32 + l4*8];
    #pragma unroll
    for (int mi = 0; mi < 4; ++mi){
      bf16x8 pa = *(const bf16x8*)&p_lds[(mi*16 + l15)*72 + ks*32 + l4*8];
      #pragma unroll
      for (int ni = 0; ni < 2; ++ni)
        o2[mi][ni] = __builtin_amdgcn_mfma_f32_16x16x32_bf16(pa, vb[ni], o2[mi][ni], 0, 0, 0);
    }
  }

  // ---- scaled store (only valid query rows) ----
  #pragma unroll
  for (int mi = 0; mi < 4; ++mi){
    #pragma unroll
    for (int r = 0; r < 4; ++r){
      int q = mi*16 + l4*4 + r;
      if (q < 49){
        float inv = 1.f / den[mi][r];
        long t = tok_lds[q];
        #pragma unroll
        for (int ni = 0; ni < 2; ++ni){
          int d = ni*16 + l15;
          attn_out[t*384 + h*32 + d] = f2b(o2[mi][ni][r] * inv);
        }
      }
    }
  }
}

extern "C" void kernel_launch(void* const* d_in, const int* in_sizes, int n_in,
                              void* d_out, int out_size, void* d_ws, size_t ws_size,
                              hipStream_t stream)
{
  const float* x_in   = (const float*)d_in[0];
  const int*   relidx = (const int*)d_in[2];
  const float* n1g    = (const float*)d_in[3];
  const float* n1b    = (const float*)d_in[4];
  const float* qkvw   = (const float*)d_in[5];
  const float* qkvb   = (const float*)d_in[6];
  const float* rpb    = (const float*)d_in[7];
  const float* pw     = (const float*)d_in[8];
  const float* pb     = (const float*)d_in[9];
  const float* n2g    = (const float*)d_in[10];
  const float* n2b    = (const float*)d_in[11];
  const float* f1w    = (const float*)d_in[12];
  const float* f1b    = (const float*)d_in[13];
  const float* f2w    = (const float*)d_in[14];
  const float* f2bb   = (const float*)d_in[15];
  float* xout = (float*)d_out;

  char* ws = (char*)d_ws;
  u16* wqkv  = (u16*)ws; ws += (size_t)2*1152*384*2;
  u16* wproj = (u16*)ws; ws += (size_t)2*384*384*2;
  u16* wfc1  = (u16*)ws; ws += (size_t)2*1536*384*2;
  u16* wfc2  = (u16*)ws; ws += (size_t)2*384*1536*2;
  u16* bufA  = (u16*)ws; ws += (size_t)M_TOK*1536*2;   // qkv (1152) / h (1536)
  u16* bufB  = (u16*)ws; ws += (size_t)M_TOK*384*2;    // xn / attn_out / h_in
  float* btbl = (float*)(bufA + (size_t)M_TOK*1152);   // tail of bufA during attn

  // convert weights to bf16
  {
    int n;
    n = 2*1152*384;  cvtw<<<dim3((n/4+255)/256), dim3(256), 0, stream>>>(qkvw, wqkv, n/4);
    n = 2*384*384;   cvtw<<<dim3((n/4+255)/256), dim3(256), 0, stream>>>(pw,   wproj, n/4);
    n = 2*1536*384;  cvtw<<<dim3((n/4+255)/256), dim3(256), 0, stream>>>(f1w,  wfc1, n/4);
    n = 2*384*1536;  cvtw<<<dim3((n/4+255)/256), dim3(256), 0, stream>>>(f2w,  wfc2, n/4);
  }

  for (int i = 0; i < 2; ++i){
    const float* xi = (i == 0) ? x_in : xout;
    // LN1 -> bufB (bf16)
    ln_kernel<<<dim3(2048), dim3(256), 0, stream>>>(xi, n1g + i*384, n1b + i*384, bufB, M_TOK);
    // QKV: bufB @ wqkv^T -> bufA  [M,1152]   grid 392*9 = 3528 (%8==0)
    gemm_bt<0><<<dim3(3528), dim3(256), 0, stream>>>(
        bufB, wqkv + (size_t)i*1152*384, qkvb + i*1152, nullptr, bufA, M_TOK, 1152, 384);
    // bias table for this block
    build_btbl<<<dim3(768), dim3(64), 0, stream>>>(rpb + (size_t)i*169*12, relidx, btbl);
    // attention: bufA -> bufB [M,384]
    if (i == 0)
      attn_mfma<0><<<dim3(12288), dim3(64), 0, stream>>>(bufA, btbl, bufB);
    else
      attn_mfma<3><<<dim3(12288), dim3(64), 0, stream>>>(bufA, btbl, bufB);
    // proj + residual: xout = xi + bufB @ wproj^T + pb   [M,384] f32  grid 1176
    gemm_bt<2><<<dim3(1176), dim3(256), 0, stream>>>(
        bufB, wproj + (size_t)i*384*384, pb + i*384, xi, xout, M_TOK, 384, 384);
    // LN2 -> bufB (bf16)
    ln_kernel<<<dim3(2048), dim3(256), 0, stream>>>(xout, n2g + i*384, n2b + i*384, bufB, M_TOK);
    // FC1 + gelu: bufB @ wfc1^T -> bufA [M,1536] bf16  grid 4704
    gemm_bt<1><<<dim3(4704), dim3(256), 0, stream>>>(
        bufB, wfc1 + (size_t)i*1536*384, f1b + i*1536, nullptr, bufA, M_TOK, 1536, 384);
    // FC2 + residual: xout += bufA @ wfc2^T + f2b  [M,384] f32  grid 1176
    gemm_bt<2><<<dim3(1176), dim3(256), 0, stream>>>(
        bufA, wfc2 + (size_t)i*384*1536, f2bb + i*384, xout, xout, M_TOK, 384, 1536);
  }
  (void)in_sizes; (void)n_in; (void)out_size; (void)ws_size;
}

// Round 6
// 965.025 us; speedup vs baseline: 1.6616x; 1.0027x over previous
//
#include <hip/hip_runtime.h>
#include <math.h>

typedef unsigned short u16;
typedef unsigned int   u32;
typedef __attribute__((ext_vector_type(4))) float f32x4;
typedef __attribute__((ext_vector_type(8))) short bf16x8;

#define M_TOK 50176
#define CDIM  384

__device__ __forceinline__ u16 f2b(float f){
  union { float f; u32 u; } v; v.f = f;
  u32 r = v.u + 0x7fffu + ((v.u >> 16) & 1u);
  return (u16)(r >> 16);
}
__device__ __forceinline__ u32 pack2(float a, float b){
  return (u32)f2b(a) | ((u32)f2b(b) << 16);
}

__device__ __forceinline__ void gload_lds16(const u16* g, u16* l){
  __builtin_amdgcn_global_load_lds((const __attribute__((address_space(1))) u32*)g,
                                   (__attribute__((address_space(3))) u32*)l, 16, 0, 0);
}

// ---------------- weight convert f32 -> bf16 ----------------
__global__ void cvtw(const float* __restrict__ in, u16* __restrict__ out, int n4){
  int i = blockIdx.x * 256 + threadIdx.x;
  if (i < n4){
    float4 v = ((const float4*)in)[i];
    uint2 o; o.x = pack2(v.x, v.y); o.y = pack2(v.z, v.w);
    ((uint2*)out)[i] = o;
  }
}

// ---------------- LayerNorm (fp32 in, bf16 out) ----------------
__global__ __launch_bounds__(256) void ln_kernel(
    const float* __restrict__ x, const float* __restrict__ g,
    const float* __restrict__ b, u16* __restrict__ out, int ntok)
{
  int wave = threadIdx.x >> 6, lane = threadIdx.x & 63;
  for (long t = blockIdx.x * 4 + wave; t < ntok; t += (long)gridDim.x * 4){
    const float* xr = x + t * CDIM;
    float v[6]; float s = 0.f, ss = 0.f;
    #pragma unroll
    for (int j = 0; j < 6; ++j){ v[j] = xr[j*64 + lane]; s += v[j]; ss += v[j]*v[j]; }
    #pragma unroll
    for (int o = 32; o >= 1; o >>= 1){ s += __shfl_xor(s, o); ss += __shfl_xor(ss, o); }
    float mean = s * (1.f/384.f);
    float var  = ss * (1.f/384.f) - mean*mean;
    float rs   = rsqrtf(var + 1e-5f);
    #pragma unroll
    for (int j = 0; j < 6; ++j){
      int c = j*64 + lane;
      out[t*CDIM + c] = f2b((v[j] - mean) * rs * g[c] + b[c]);
    }
  }
}

// ---------------- GEMM out[m,n] = sum_k A[m,k]*W[n,k] (+bias, epilogue) ----
// T1: bijective XCD-chunked swizzle on 1-D grid (grid%8==0).
// T3/T4: double-buffered LDS, counted vmcnt(4), raw barriers.
// LDS swizzle: chunk ^= (row>>1)&3 on stage-source AND read -> 2-way (free).
// bf16 epilogues bounce through LDS then NONTEMPORAL coalesced stores:
// the 115-154MB qkv/h output streams must not evict the L3-resident A-panels
// (round-5 counters: FETCH = 4x ideal-A from write-stream eviction).
// EPI 0: bf16 (bias)   1: bf16 (bias+exact gelu)   2: f32 (bias + resid)
template<int EPI>
__global__ __launch_bounds__(256, 4) void gemm_bt(
    const u16* __restrict__ A, const u16* __restrict__ Wt,
    const float* __restrict__ bias, const float* __restrict__ resid,
    void* __restrict__ outp, int M, int N, int K)
{
  __shared__ __align__(16) u16 smem[16384];   // 32 KB: [A0|A1|B0|B1] / epi 128x128
  const int tid  = threadIdx.x;
  const int wave = tid >> 6, lane = tid & 63;
  const int nbn  = N >> 7;
  const int cpx  = gridDim.x >> 3;
  const int sid  = (blockIdx.x & 7) * cpx + (blockIdx.x >> 3);
  const int bm = sid / nbn, bn = sid % nbn;   // bn fastest within an XCD chunk
  const int wr = wave >> 1, wc = wave & 1;
  const int l15 = lane & 15, l4 = lane >> 4;
  const int srow = tid >> 2, sch = tid & 3;

  f32x4 acc[4][4] = {};

  auto STAGE = [&](int buf, int kt){
    u16* lAp = smem + buf*4096;
    u16* lBp = smem + 8192 + buf*4096;
    #pragma unroll
    for (int it = 0; it < 2; ++it){
      int row = it*64 + srow;
      int chs = sch ^ ((srow >> 1) & 3);         // pre-swizzled source chunk
      const u16* ga = A  + (size_t)(bm*128 + row) * K + kt + chs*8;
      const u16* gb = Wt + (size_t)(bn*128 + row) * K + kt + chs*8;
      gload_lds16(ga, &lAp[(it*256 + wave*64) * 8]);
      gload_lds16(gb, &lBp[(it*256 + wave*64) * 8]);
    }
  };

  const int NK = K >> 5;
  STAGE(0, 0);

  int cur = 0;
  for (int ki = 0; ki < NK; ++ki){
    if (ki + 1 < NK){
      STAGE(cur ^ 1, (ki + 1) * 32);
      asm volatile("s_waitcnt vmcnt(4)" ::: "memory");  // prev STAGE done; new 4 in flight
    } else {
      asm volatile("s_waitcnt vmcnt(0)" ::: "memory");
    }
    __builtin_amdgcn_s_barrier();                       // buf[cur] visible to all
    const u16* lAp = smem + cur*4096;
    const u16* lBp = smem + 8192 + cur*4096;
    bf16x8 af[4], bfr[4];
    const int rc = (l4 ^ ((l15 >> 1) & 3)) * 8;         // swizzled 16B chunk
    #pragma unroll
    for (int mi = 0; mi < 4; ++mi)
      af[mi] = *(const bf16x8*)&lAp[(wr*64 + mi*16 + l15)*32 + rc];
    #pragma unroll
    for (int ni = 0; ni < 4; ++ni)
      bfr[ni] = *(const bf16x8*)&lBp[(wc*64 + ni*16 + l15)*32 + rc];
    #pragma unroll
    for (int mi = 0; mi < 4; ++mi)
      #pragma unroll
      for (int ni = 0; ni < 4; ++ni)
        acc[mi][ni] = __builtin_amdgcn_mfma_f32_16x16x32_bf16(af[mi], bfr[ni], acc[mi][ni], 0, 0, 0);
    __builtin_amdgcn_s_barrier();                       // reads of buf[cur] done (WAR)
    cur ^= 1;
  }

  if (EPI == 2){
    // f32 + residual: 16 lanes x 4B = full 64B lines already; stays cached
    #pragma unroll
    for (int ni = 0; ni < 4; ++ni){
      int col = bn*128 + wc*64 + ni*16 + l15;
      float bb = bias[col];
      #pragma unroll
      for (int mi = 0; mi < 4; ++mi){
        int row0 = bm*128 + wr*64 + mi*16 + l4*4;
        #pragma unroll
        for (int r = 0; r < 4; ++r){
          long off = (long)(row0 + r) * N + col;
          ((float*)outp)[off] = resid[off] + acc[mi][ni][r] + bb;
        }
      }
    }
  } else {
    // bf16: bounce through LDS (XOR col^(l4*16)) -> coalesced NT u32 stores
    #pragma unroll
    for (int ni = 0; ni < 4; ++ni){
      int colL = wc*64 + ni*16 + l15;
      float bb = bias[bn*128 + colL];
      int colS = colL ^ (l4*16);
      #pragma unroll
      for (int mi = 0; mi < 4; ++mi){
        int rowL = wr*64 + mi*16 + l4*4;
        #pragma unroll
        for (int r = 0; r < 4; ++r){
          float v = acc[mi][ni][r] + bb;
          if (EPI == 1) v = 0.5f * v * (1.f + erff(v * 0.70710678118654752f));
          smem[(rowL + r)*128 + colS] = f2b(v);
        }
      }
    }
    __syncthreads();
    const u32* eb = (const u32*)smem;
    u32* og = (u32*)outp;
    const int nW = N >> 1;
    #pragma unroll
    for (int it = 0; it < 32; ++it){
      int row = wave*32 + it;
      u32 w = eb[row*64 + (lane ^ (((row >> 2) & 3) * 8))];
      __builtin_nontemporal_store(w, &og[(size_t)(bm*128 + row) * nW + bn*64 + lane]);
    }
  }
}

// ---------------- bias table: btbl[h][q][l15*4+ni] = rpb[ridx[q][key]][h],
//                  key = ni*16+l15; -1e9 for q>=49 or key>=49 (padding mask)
__global__ void build_btbl(const float* __restrict__ rpb, const int* __restrict__ ridx,
                           float* __restrict__ btbl){
  int q = blockIdx.x & 63, h = blockIdx.x >> 6;
  int l = threadIdx.x;
  float v = -1e9f;
  if (q < 49){
    int key = (l & 3) * 16 + (l >> 2);
    if (key < 49) v = rpb[ridx[q*49 + key] * 12 + h];
  }
  btbl[(h*64 + q)*64 + l] = v;
}

// ---------------- MFMA windowed attention: one wave = one (window, head) ----
template<int SHIFT>
__global__ __launch_bounds__(64) void attn_mfma(
    const u16* __restrict__ qkv,     // [M_TOK][1152] bf16
    const float* __restrict__ btbl,  // [12][64][64] f32 (this block's table)
    u16* __restrict__ attn_out)      // [M_TOK][384] bf16
{
  __shared__ __align__(16) u16 p_lds[64*72];   // P[q][m] bf16, stride 72
  __shared__ __align__(16) u16 vt_lds[32*72];  // V^T[d][m] bf16, stride 72
  __shared__ int tok_lds[64];
  __shared__ int rid_lds[64];

  const int bid = blockIdx.x;
  const int h   = bid % 12;
  const int win = bid / 12;
  const int b   = win >> 6, wl = win & 63;
  const int wy  = wl >> 3,  wx = wl & 7;
  const int lane = threadIdx.x;
  const int l15 = lane & 15, l4 = lane >> 4;

  auto tokof = [&](int n)->int{
    int r = (n * 9363) >> 16;      // n/7 for n<=48
    int c = n - r * 7;
    int hh = wy*7 + r + SHIFT; if (hh >= 56) hh -= 56;
    int ww = wx*7 + c + SHIFT; if (ww >= 56) ww -= 56;
    return b*3136 + hh*56 + ww;
  };

  // ---- staging: V^T (zero-padded cols >=49), token table, region ids ----
  {
    const int n  = lane;
    const int nc = n < 49 ? n : 48;
    const int t  = tokof(nc);
    tok_lds[n] = t;
    if (SHIFT){
      int r = (nc * 9363) >> 16, c = nc - r*7;
      int gh = wy*7 + r, gw = wx*7 + c;
      int rh = gh <= 48 ? 0 : (gh <= 52 ? 1 : 2);
      int rw = gw <= 48 ? 0 : (gw <= 52 ? 1 : 2);
      rid_lds[n] = rh*3 + rw;
    }
    const uint4* vp = (const uint4*)(qkv + (size_t)t*1152 + 768 + h*32);
    u32 w[16];
    #pragma unroll
    for (int j4 = 0; j4 < 4; ++j4){
      uint4 u = vp[j4];
      w[j4*4+0]=u.x; w[j4*4+1]=u.y; w[j4*4+2]=u.z; w[j4*4+3]=u.w;
    }
    if (n >= 49){
      #pragma unroll
      for (int j = 0; j < 16; ++j) w[j] = 0;
    }
    #pragma unroll
    for (int j = 0; j < 16; ++j){
      vt_lds[(2*j  )*72 + n] = (u16)(w[j] & 0xffffu);
      vt_lds[(2*j+1)*72 + n] = (u16)(w[j] >> 16);
    }
  }

  // ---- QK^T fragments directly from global ----
  bf16x8 qa[4], kb[4];
  #pragma unroll
  for (int mi = 0; mi < 4; ++mi){
    int row = mi*16 + l15; int t = tokof(row < 49 ? row : 48);
    qa[mi] = *(const bf16x8*)(qkv + (size_t)t*1152 + h*32 + l4*8);
  }
  #pragma unroll
  for (int ni = 0; ni < 4; ++ni){
    int row = ni*16 + l15; int t = tokof(row < 49 ? row : 48);
    kb[ni] = *(const bf16x8*)(qkv + (size_t)t*1152 + 384 + h*32 + l4*8);
  }
  f32x4 s[4][4] = {};
  #pragma unroll
  for (int mi = 0; mi < 4; ++mi)
    #pragma unroll
    for (int ni = 0; ni < 4; ++ni)
      s[mi][ni] = __builtin_amdgcn_mfma_f32_16x16x32_bf16(qa[mi], kb[ni], s[mi][ni], 0, 0, 0);

  __syncthreads();   // staging (V^T / tok / rid) complete

  int rid_k[4];
  if (SHIFT){
    #pragma unroll
    for (int ni = 0; ni < 4; ++ni) rid_k[ni] = rid_lds[ni*16 + l15];
  }

  // ---- scale + bias + mask, row softmax in-register ----
  const float* bt = btbl + h*4096;
  float den[4][4];
  #pragma unroll
  for (int mi = 0; mi < 4; ++mi){
    #pragma unroll
    for (int r = 0; r < 4; ++r){
      int q = mi*16 + l4*4 + r;
      f32x4 bq = *(const f32x4*)(bt + q*64 + l15*4);
      int ridq = 0;
      if (SHIFT) ridq = rid_lds[q];
      #pragma unroll
      for (int ni = 0; ni < 4; ++ni){
        float v = s[mi][ni][r] * 0.17677669529663687f + bq[ni];
        if (SHIFT) v += (ridq == rid_k[ni]) ? 0.f : -100.f;
        s[mi][ni][r] = v;
      }
      float m0 = fmaxf(fmaxf(s[mi][0][r], s[mi][1][r]), fmaxf(s[mi][2][r], s[mi][3][r]));
      #pragma unroll
      for (int o = 1; o <= 8; o <<= 1) m0 = fmaxf(m0, __shfl_xor(m0, o));
      float d0 = 0.f;
      #pragma unroll
      for (int ni = 0; ni < 4; ++ni){
        float e = __expf(s[mi][ni][r] - m0);
        s[mi][ni][r] = e; d0 += e;
      }
      #pragma unroll
      for (int o = 1; o <= 8; o <<= 1) d0 += __shfl_xor(d0, o);
      den[mi][r] = d0;
    }
  }

  // ---- pack P to LDS (bf16, stride 72) ----
  #pragma unroll
  for (int mi = 0; mi < 4; ++mi)
    #pragma unroll
    for (int r = 0; r < 4; ++r){
      int q = mi*16 + l4*4 + r;
      #pragma unroll
      for (int ni = 0; ni < 4; ++ni)
        p_lds[q*72 + ni*16 + l15] = f2b(s[mi][ni][r]);
    }

  __syncthreads();   // P writes complete

  // ---- PV via MFMA: O[q][d] = sum_m P[q][m] * VT[d][m] ----
  f32x4 o2[4][2] = {};
  #pragma unroll
  for (int ks = 0; ks < 2; ++ks){
    bf16x8 vb[2];
    #pragma unroll
    for (int ni = 0; ni < 2; ++ni)
      vb[ni] = *(const bf16x8*)&vt_lds[(ni*16 + l15)*72 + ks*32 + l4*8];
    #pragma unroll
    for (int mi = 0; mi < 4; ++mi){
      bf16x8 pa = *(const bf16x8*)&p_lds[(mi*16 + l15)*72 + ks*32 + l4*8];
      #pragma unroll
      for (int ni = 0; ni < 2; ++ni)
        o2[mi][ni] = __builtin_amdgcn_mfma_f32_16x16x32_bf16(pa, vb[ni], o2[mi][ni], 0, 0, 0);
    }
  }

  // ---- scaled store (only valid query rows) ----
  #pragma unroll
  for (int mi = 0; mi < 4; ++mi){
    #pragma unroll
    for (int r = 0; r < 4; ++r){
      int q = mi*16 + l4*4 + r;
      if (q < 49){
        float inv = 1.f / den[mi][r];
        long t = tok_lds[q];
        #pragma unroll
        for (int ni = 0; ni < 2; ++ni){
          int d = ni*16 + l15;
          attn_out[t*384 + h*32 + d] = f2b(o2[mi][ni][r] * inv);
        }
      }
    }
  }
}

extern "C" void kernel_launch(void* const* d_in, const int* in_sizes, int n_in,
                              void* d_out, int out_size, void* d_ws, size_t ws_size,
                              hipStream_t stream)
{
  const float* x_in   = (const float*)d_in[0];
  const int*   relidx = (const int*)d_in[2];
  const float* n1g    = (const float*)d_in[3];
  const float* n1b    = (const float*)d_in[4];
  const float* qkvw   = (const float*)d_in[5];
  const float* qkvb   = (const float*)d_in[6];
  const float* rpb    = (const float*)d_in[7];
  const float* pw     = (const float*)d_in[8];
  const float* pb     = (const float*)d_in[9];
  const float* n2g    = (const float*)d_in[10];
  const float* n2b    = (const float*)d_in[11];
  const float* f1w    = (const float*)d_in[12];
  const float* f1b    = (const float*)d_in[13];
  const float* f2w    = (const float*)d_in[14];
  const float* f2bb   = (const float*)d_in[15];
  float* xout = (float*)d_out;

  char* ws = (char*)d_ws;
  u16* wqkv  = (u16*)ws; ws += (size_t)2*1152*384*2;
  u16* wproj = (u16*)ws; ws += (size_t)2*384*384*2;
  u16* wfc1  = (u16*)ws; ws += (size_t)2*1536*384*2;
  u16* wfc2  = (u16*)ws; ws += (size_t)2*384*1536*2;
  u16* bufA  = (u16*)ws; ws += (size_t)M_TOK*1536*2;   // qkv (1152) / h (1536)
  u16* bufB  = (u16*)ws; ws += (size_t)M_TOK*384*2;    // xn / attn_out / h_in
  float* btbl = (float*)(bufA + (size_t)M_TOK*1152);   // tail of bufA during attn

  // convert weights to bf16
  {
    int n;
    n = 2*1152*384;  cvtw<<<dim3((n/4+255)/256), dim3(256), 0, stream>>>(qkvw, wqkv, n/4);
    n = 2*384*384;   cvtw<<<dim3((n/4+255)/256), dim3(256), 0, stream>>>(pw,   wproj, n/4);
    n = 2*1536*384;  cvtw<<<dim3((n/4+255)/256), dim3(256), 0, stream>>>(f1w,  wfc1, n/4);
    n = 2*384*1536;  cvtw<<<dim3((n/4+255)/256), dim3(256), 0, stream>>>(f2w,  wfc2, n/4);
  }

  for (int i = 0; i < 2; ++i){
    const float* xi = (i == 0) ? x_in : xout;
    // LN1 -> bufB (bf16)
    ln_kernel<<<dim3(2048), dim3(256), 0, stream>>>(xi, n1g + i*384, n1b + i*384, bufB, M_TOK);
    // QKV: bufB @ wqkv^T -> bufA  [M,1152]   grid 392*9 = 3528 (%8==0)
    gemm_bt<0><<<dim3(3528), dim3(256), 0, stream>>>(
        bufB, wqkv + (size_t)i*1152*384, qkvb + i*1152, nullptr, bufA, M_TOK, 1152, 384);
    // bias table for this block
    build_btbl<<<dim3(768), dim3(64), 0, stream>>>(rpb + (size_t)i*169*12, relidx, btbl);
    // attention: bufA -> bufB [M,384]
    if (i == 0)
      attn_mfma<0><<<dim3(12288), dim3(64), 0, stream>>>(bufA, btbl, bufB);
    else
      attn_mfma<3><<<dim3(12288), dim3(64), 0, stream>>>(bufA, btbl, bufB);
    // proj + residual: xout = xi + bufB @ wproj^T + pb   [M,384] f32  grid 1176
    gemm_bt<2><<<dim3(1176), dim3(256), 0, stream>>>(
        bufB, wproj + (size_t)i*384*384, pb + i*384, xi, xout, M_TOK, 384, 384);
    // LN2 -> bufB (bf16)
    ln_kernel<<<dim3(2048), dim3(256), 0, stream>>>(xout, n2g + i*384, n2b + i*384, bufB, M_TOK);
    // FC1 + gelu: bufB @ wfc1^T -> bufA [M,1536] bf16  grid 4704
    gemm_bt<1><<<dim3(4704), dim3(256), 0, stream>>>(
        bufB, wfc1 + (size_t)i*1536*384, f1b + i*1536, nullptr, bufA, M_TOK, 1536, 384);
    // FC2 + residual: xout += bufA @ wfc2^T + f2b  [M,384] f32  grid 1176
    gemm_bt<2><<<dim3(1176), dim3(256), 0, stream>>>(
        bufA, wfc2 + (size_t)i*384*1536, f2bb + i*384, xout, xout, M_TOK, 384, 1536);
  }
  (void)in_sizes; (void)n_in; (void)out_size; (void)ws_size;
}